// Round 4
// baseline (606.560 us; speedup 1.0000x reference)
//
#include <hip/hip_runtime.h>
#include <math.h>

// ---------------------------------------------------------------------------
// GCN forward: 3x GCNConv (sym-norm, self-loops) + linear + global max pool.
// N=50000, E=800000, F=256, H=128, O=64, fp32 in/out.
//
// R4: intermediates stored column-chunked [8][N][16] so the per-chunk gather
// working set (3.2 MB) fits per-XCD L2. Agg grid = (dst_blocks, chunk) with
// chunk slow-varying -> temporal chunk separation -> gathers hit L2.
// GEMMs (split-fp16 MFMA, 3-pass) read/write the chunked layout.
// ---------------------------------------------------------------------------

typedef __attribute__((ext_vector_type(8))) _Float16 f16x8;
typedef __attribute__((ext_vector_type(4))) float f32x4;

__device__ __forceinline__ void split_f16(float a, unsigned short& h, unsigned short& l) {
    _Float16 ah = (_Float16)a;          // RNE
    float r = a - (float)ah;            // exact (Sterbenz)
    _Float16 al = (_Float16)r;          // RNE
    h = __builtin_bit_cast(unsigned short, ah);
    l = __builtin_bit_cast(unsigned short, al);
}

__device__ __forceinline__ unsigned enc_f32(float f) {
    unsigned u = __float_as_uint(f);
    return (u & 0x80000000u) ? ~u : (u | 0x80000000u);
}
__device__ __forceinline__ float dec_f32(unsigned e) {
    return (e & 0x80000000u) ? __uint_as_float(e & 0x7fffffffu)
                             : __uint_as_float(~e);
}
#define ENC_NEG_INF 0x007FFFFFu  // enc(-inf)

// ---------------------------------------------------------------- small utils
__global__ void k_init_gmax(unsigned* __restrict__ g) {
    g[threadIdx.x] = ENC_NEG_INF;
}

__global__ void k_count(const int* __restrict__ dst, int* __restrict__ counts, int E) {
    int e = blockIdx.x * blockDim.x + threadIdx.x;
    if (e < E) atomicAdd(&counts[dst[e]], 1);
}

__global__ void k_dinv(const int* __restrict__ counts, float* __restrict__ dinv, int N) {
    int i = blockIdx.x * blockDim.x + threadIdx.x;
    if (i < N) dinv[i] = rsqrtf((float)(counts[i] + 1));  // +1 self-loop
}

// -------------------------------------------------------------- 3-pass scan
__global__ __launch_bounds__(1024) void k_scan1(const int* __restrict__ counts,
                                                int* __restrict__ excl,
                                                int* __restrict__ bsums, int N) {
    __shared__ int sh[1024];
    int t = threadIdx.x;
    int i = blockIdx.x * 1024 + t;
    int v = (i < N) ? counts[i] : 0;
    sh[t] = v;
    __syncthreads();
    for (int off = 1; off < 1024; off <<= 1) {
        int tv = (t >= off) ? sh[t - off] : 0;
        __syncthreads();
        sh[t] += tv;
        __syncthreads();
    }
    if (i < N) excl[i] = sh[t] - v;
    if (t == 1023) bsums[blockIdx.x] = sh[1023];
}

__global__ void k_scan2(const int* __restrict__ bsums, int* __restrict__ bofs, int nb) {
    __shared__ int sh[64];
    int t = threadIdx.x;
    int v = (t < nb) ? bsums[t] : 0;
    sh[t] = v;
    __syncthreads();
    for (int off = 1; off < 64; off <<= 1) {
        int tv = (t >= off) ? sh[t - off] : 0;
        __syncthreads();
        sh[t] += tv;
        __syncthreads();
    }
    if (t < nb) bofs[t] = sh[t] - v;
}

__global__ void k_scan3(int* __restrict__ rofs, int* __restrict__ pos,
                        const int* __restrict__ bofs, int N, int E) {
    int i = blockIdx.x * blockDim.x + threadIdx.x;
    if (i < N) {
        int v = rofs[i] + bofs[i >> 10];
        rofs[i] = v;
        pos[i]  = v;
    }
    if (i == 0) rofs[N] = E;
}

__global__ void k_fill(const int* __restrict__ src, const int* __restrict__ dst,
                       int* __restrict__ pos, int* __restrict__ csr, int E) {
    int e = blockIdx.x * blockDim.x + threadIdx.x;
    if (e < E) {
        int p = atomicAdd(&pos[dst[e]], 1);
        csr[p] = src[e];
    }
}

// ------------------------------------------------------------ weight packing
// W[K][M] fp32 -> hi/lo f16 planes in MFMA B-frag order.
template <int K, int M>
__global__ void k_packw(const float* __restrict__ W, unsigned short* __restrict__ Wh,
                        unsigned short* __restrict__ Wl) {
    int c = blockIdx.x % (M / 16);
    int q = blockIdx.x / (M / 16);
    int l = threadIdx.x;  // 64
    int n = c * 16 + (l & 15);
    int k0 = q * 32 + (l >> 4) * 8;
    size_t base = ((size_t)(c * (K / 32) + q) * 64 + l) * 8;
#pragma unroll
    for (int j = 0; j < 8; ++j) {
        unsigned short h, lo;
        split_f16(W[(size_t)(k0 + j) * M + n], h, lo);
        Wh[base + j] = h;
        Wl[base + j] = lo;
    }
}

// -------------------------------------------------------------------- GEMM
// 128-row block tile, 4 waves in 2x2, wave tile 64 x (M/2). Split-f16, 3-pass.
// ALAY=0: A row-major [N][K].  ALAY=1: A chunked [(K/16)][N][16].
// EPI=0: out (chunked [(M/16)][N][16]) = sc[r] * (A W)
// EPI=1: gmax[c] max= (A W)[r][c] + sc[c]   (encoded atomicMax)
template <int K, int M, int EPI, int ALAY>
__global__ __launch_bounds__(256, 2) void k_gemm(const float* __restrict__ A,
                                                 const unsigned short* __restrict__ Wh,
                                                 const unsigned short* __restrict__ Wl,
                                                 const float* __restrict__ sc,
                                                 float* __restrict__ out,
                                                 unsigned* __restrict__ gmax,
                                                 int N) {
    constexpr int CT = M / 32;  // col-tiles per wave
    constexpr int QK = K / 32;  // k chunks
    __shared__ unsigned short Ah[128 * 32], Al[128 * 32];  // frag order [tile][lane][j]
    __shared__ unsigned short Bh[M * 32], Bl[M * 32];
    __shared__ unsigned smax[64];
    const int tid = threadIdx.x;
    const int lane = tid & 63;
    const int wave = tid >> 6;
    const int wrow = wave >> 1;
    const int wcol = wave & 1;
    const int R0 = blockIdx.x * 128;

    f32x4 acc[4][CT];
#pragma unroll
    for (int rt = 0; rt < 4; ++rt)
#pragma unroll
        for (int ct = 0; ct < CT; ++ct) acc[rt][ct] = (f32x4){0.f, 0.f, 0.f, 0.f};

    for (int q = 0; q < QK; ++q) {
        const int k0 = q * 32;
        // ---- stage A: fp32 load (coalesced), split, frag-order LDS store ----
#pragma unroll
        for (int it = 0; it < 4; ++it) {
            int idx = tid + it * 256;  // 0..1023
            int r = idx >> 3;
            int kk = (idx & 7) << 2;   // 0,4,...,28
            float4 g = {0.f, 0.f, 0.f, 0.f};
            if (R0 + r < N) {
                int k = k0 + kk;
                size_t ad = ALAY ? (((size_t)(k >> 4) * N + (R0 + r)) * 16 + (k & 15))
                                 : ((size_t)(R0 + r) * K + k);
                g = *(const float4*)&A[ad];
            }
            unsigned short h0, h1, h2, h3, l0, l1, l2, l3;
            split_f16(g.x, h0, l0);
            split_f16(g.y, h1, l1);
            split_f16(g.z, h2, l2);
            split_f16(g.w, h3, l3);
            int fo = ((r >> 4) << 9) + ((((kk >> 3) << 4) | (r & 15)) << 3) + (kk & 7);
            uint2 uh, ul;
            uh.x = (unsigned)h0 | ((unsigned)h1 << 16);
            uh.y = (unsigned)h2 | ((unsigned)h3 << 16);
            ul.x = (unsigned)l0 | ((unsigned)l1 << 16);
            ul.y = (unsigned)l2 | ((unsigned)l3 << 16);
            *(uint2*)&Ah[fo] = uh;
            *(uint2*)&Al[fo] = ul;
        }
        // ---- stage B: pre-packed, straight 16B copies ----
#pragma unroll
        for (int it = 0; it < M / 64; ++it) {
            int idx = tid + it * 256;
            int c = idx >> 6;
            int l = idx & 63;
            size_t gflat = ((size_t)(c * QK + q) * 64 + l) * 8;
            int lflat = (c * 64 + l) * 8;
            *(uint4*)&Bh[lflat] = *(const uint4*)&Wh[gflat];
            *(uint4*)&Bl[lflat] = *(const uint4*)&Wl[gflat];
        }
        __syncthreads();
        // ---- frags + 3-pass mfma ----
        f16x8 ahf[4], alf[4], bhf[CT], blf[CT];
#pragma unroll
        for (int rt = 0; rt < 4; ++rt) {
            int t = wrow * 4 + rt;
            ahf[rt] = *(const f16x8*)&Ah[(t * 64 + lane) * 8];
            alf[rt] = *(const f16x8*)&Al[(t * 64 + lane) * 8];
        }
#pragma unroll
        for (int ct = 0; ct < CT; ++ct) {
            int t = wcol * CT + ct;
            bhf[ct] = *(const f16x8*)&Bh[(t * 64 + lane) * 8];
            blf[ct] = *(const f16x8*)&Bl[(t * 64 + lane) * 8];
        }
#pragma unroll
        for (int rt = 0; rt < 4; ++rt)
#pragma unroll
            for (int ct = 0; ct < CT; ++ct) {
                acc[rt][ct] = __builtin_amdgcn_mfma_f32_16x16x32_f16(ahf[rt], bhf[ct], acc[rt][ct], 0, 0, 0);
                acc[rt][ct] = __builtin_amdgcn_mfma_f32_16x16x32_f16(ahf[rt], blf[ct], acc[rt][ct], 0, 0, 0);
                acc[rt][ct] = __builtin_amdgcn_mfma_f32_16x16x32_f16(alf[rt], bhf[ct], acc[rt][ct], 0, 0, 0);
            }
        __syncthreads();
    }

    const int quad = lane >> 4;
    if (EPI == 0) {
#pragma unroll
        for (int rt = 0; rt < 4; ++rt)
#pragma unroll
            for (int reg = 0; reg < 4; ++reg) {
                int r = R0 + wrow * 64 + rt * 16 + quad * 4 + reg;
                if (r < N) {
                    float s = sc[r];
#pragma unroll
                    for (int ct = 0; ct < CT; ++ct) {
                        int ch = wcol * CT + ct;  // 16-col chunk index
                        out[((size_t)ch * N + r) * 16 + (lane & 15)] = acc[rt][ct][reg] * s;
                    }
                }
            }
    } else {
        if (tid < 64) smax[tid] = ENC_NEG_INF;
        __syncthreads();
        float cm[CT];
#pragma unroll
        for (int ct = 0; ct < CT; ++ct) cm[ct] = -INFINITY;
#pragma unroll
        for (int rt = 0; rt < 4; ++rt)
#pragma unroll
            for (int reg = 0; reg < 4; ++reg) {
                int r = R0 + wrow * 64 + rt * 16 + quad * 4 + reg;
                if (r < N) {
#pragma unroll
                    for (int ct = 0; ct < CT; ++ct) cm[ct] = fmaxf(cm[ct], acc[rt][ct][reg]);
                }
            }
#pragma unroll
        for (int ct = 0; ct < CT; ++ct) {
            float v = cm[ct];
            v = fmaxf(v, __shfl_xor(v, 16, 64));
            v = fmaxf(v, __shfl_xor(v, 32, 64));
            if (lane < 16) {
                int c = wcol * (CT * 16) + ct * 16 + lane;
                atomicMax(&smax[c], enc_f32(v + sc[c]));
            }
        }
        __syncthreads();
        if (tid < 64) atomicMax(&gmax[tid], smax[tid]);
    }
}

__global__ void k_decode(const unsigned* __restrict__ g, float* __restrict__ out) {
    out[threadIdx.x] = dec_f32(g[threadIdx.x]);
}

// ------------------------------------------------------------- aggregation
// Chunked: tmp/out are [(H/16)][N][16]. grid = (ceil(N/16), 8 chunks), chunk
// on blockIdx.y (slow-varying) -> per-chunk gather working set 3.2 MB ~ L2.
// Block: 4 waves x 4 dst/wave (16 lanes per dst, 1 float each).
__global__ __launch_bounds__(256) void k_agg_c(const float* __restrict__ tmp,
                                               const float* __restrict__ dinv,
                                               const int* __restrict__ rofs,
                                               const int* __restrict__ csr,
                                               const float* __restrict__ bias,
                                               float* __restrict__ out, int N) {
    const int lane = threadIdx.x & 63;
    const int wave = threadIdx.x >> 6;
    const int g = lane >> 4;     // dst slot within wave
    const int j = lane & 15;     // feature within chunk
    const int c = blockIdx.y;    // chunk
    const int d = blockIdx.x * 16 + wave * 4 + g;
    if (d >= N) return;
    const float* __restrict__ base = tmp + (size_t)c * N * 16;
    int beg = rofs[d], end = rofs[d + 1];
    float a0 = 0.f, a1 = 0.f;
    int e = beg;
    for (; e + 2 <= end; e += 2) {
        int s0 = csr[e], s1 = csr[e + 1];
        a0 += base[(size_t)s0 * 16 + j];
        a1 += base[(size_t)s1 * 16 + j];
    }
    if (e < end) a0 += base[(size_t)csr[e] * 16 + j];
    float self = base[(size_t)d * 16 + j];
    float v = fmaf(dinv[d], a0 + a1 + self, bias[c * 16 + j]);
    out[((size_t)c * N + d) * 16 + j] = v;
}

// ---------------------------------------------------------------------------
extern "C" void kernel_launch(void* const* d_in, const int* in_sizes, int n_in,
                              void* d_out, int out_size, void* d_ws, size_t ws_size,
                              hipStream_t stream) {
    const float* x    = (const float*)d_in[0];
    const int*   ei   = (const int*)d_in[1];  // [2,E]: row0=src, row1=dst
    const float* W0   = (const float*)d_in[3];
    const float* b0   = (const float*)d_in[4];
    const float* W1   = (const float*)d_in[5];
    const float* b1   = (const float*)d_in[6];
    const float* W2   = (const float*)d_in[7];
    const float* b2   = (const float*)d_in[8];
    const float* Wlin = (const float*)d_in[9];
    const float* blin = (const float*)d_in[10];
    float* out = (float*)d_out;

    const int N = in_sizes[2];
    const int E = in_sizes[1] / 2;
    const int* src = ei;
    const int* dst = ei + E;

    size_t off = 0;
    auto carve = [&](size_t bytes) {
        void* p = (char*)d_ws + off;
        off += (bytes + 255) & ~(size_t)255;
        return p;
    };
    int*      counts = (int*)carve((size_t)N * 4);
    int*      pos    = (int*)carve((size_t)N * 4);
    float*    dinv   = (float*)carve((size_t)N * 4);
    int*      rofs   = (int*)carve((size_t)(N + 1) * 4);
    int*      bsums  = (int*)carve(64 * 4);
    int*      bofs   = (int*)carve(64 * 4);
    int*      csr    = (int*)carve((size_t)E * 4);
    float*    tmpA   = (float*)carve((size_t)N * 128 * 4);
    float*    tmpB   = (float*)carve((size_t)N * 128 * 4);
    unsigned* gmax   = (unsigned*)carve(64 * 4);
    unsigned short* w0h = (unsigned short*)carve(256 * 128 * 2);
    unsigned short* w0l = (unsigned short*)carve(256 * 128 * 2);
    unsigned short* w1h = (unsigned short*)carve(128 * 128 * 2);
    unsigned short* w1l = (unsigned short*)carve(128 * 128 * 2);
    unsigned short* w2h = (unsigned short*)carve(128 * 128 * 2);
    unsigned short* w2l = (unsigned short*)carve(128 * 128 * 2);
    unsigned short* wlh = (unsigned short*)carve(128 * 64 * 2);
    unsigned short* wll = (unsigned short*)carve(128 * 64 * 2);
    (void)ws_size; (void)n_in; (void)out_size;

    const int nbE  = (E + 255) / 256;
    const int nbN  = (N + 255) / 256;
    const int nbS  = (N + 1023) / 1024;
    const int nbG  = (N + 127) / 128;
    const int nbA  = (N + 15) / 16;  // agg: 16 dst per block
    dim3 gridAgg(nbA, 8);

    hipMemsetAsync(counts, 0, (size_t)N * 4, stream);
    k_init_gmax<<<1, 64, 0, stream>>>(gmax);

    // weight packing (tiny)
    k_packw<256, 128><<<(128 / 16) * (256 / 32), 64, 0, stream>>>(W0, w0h, w0l);
    k_packw<128, 128><<<(128 / 16) * (128 / 32), 64, 0, stream>>>(W1, w1h, w1l);
    k_packw<128, 128><<<(128 / 16) * (128 / 32), 64, 0, stream>>>(W2, w2h, w2l);
    k_packw<128, 64><<<(64 / 16) * (128 / 32), 64, 0, stream>>>(Wlin, wlh, wll);

    // graph structure
    k_count<<<nbE, 256, 0, stream>>>(dst, counts, E);
    k_dinv<<<nbN, 256, 0, stream>>>(counts, dinv, N);
    k_scan1<<<nbS, 1024, 0, stream>>>(counts, rofs, bsums, N);
    k_scan2<<<1, 64, 0, stream>>>(bsums, bofs, nbS);
    k_scan3<<<nbN, 256, 0, stream>>>(rofs, pos, bofs, N, E);
    k_fill<<<nbE, 256, 0, stream>>>(src, dst, pos, csr, E);

    // layer 1 (A row-major x, out chunked)
    k_gemm<256, 128, 0, 0><<<nbG, 256, 0, stream>>>(x, w0h, w0l, dinv, tmpA, nullptr, N);
    k_agg_c<<<gridAgg, 256, 0, stream>>>(tmpA, dinv, rofs, csr, b0, tmpB, N);
    // layer 2 (A chunked)
    k_gemm<128, 128, 0, 1><<<nbG, 256, 0, stream>>>(tmpB, w1h, w1l, dinv, tmpA, nullptr, N);
    k_agg_c<<<gridAgg, 256, 0, stream>>>(tmpA, dinv, rofs, csr, b1, tmpB, N);
    // layer 3 (A chunked)
    k_gemm<128, 128, 0, 1><<<nbG, 256, 0, stream>>>(tmpB, w2h, w2l, dinv, tmpA, nullptr, N);
    k_agg_c<<<gridAgg, 256, 0, stream>>>(tmpA, dinv, rofs, csr, b2, tmpB, N);
    // linear + global max pool (A chunked)
    k_gemm<128, 64, 1, 1><<<nbG, 256, 0, stream>>>(tmpB, wlh, wll, blin, nullptr, gmax, N);
    k_decode<<<1, 64, 0, stream>>>(gmax, out);
}

// Round 5
// 462.118 us; speedup vs baseline: 1.3126x; 1.3126x over previous
//
#include <hip/hip_runtime.h>
#include <math.h>

// ---------------------------------------------------------------------------
// GCN forward: 3x GCNConv (sym-norm, self-loops) + linear + global max pool.
// N=50000, E=800000, F=256, H=128, O=64, fp32 in/out.
//
// R5: row-major everywhere (R4 chunking reverted — per-XCD reuse is only ~2x,
// so L2-fill floor ~200MB is already met; limiter is outstanding-bytes/instr).
// k_agg gathers with dwordx4: 32 lanes per row, 2 edges per instruction
// (1KB/instr), 8 edges (4KB) in flight per wave, shfl_xor(32) combine.
// GEMMs: split-fp16 MFMA 3-pass (hi*hi + hi*lo + lo*hi), ~2^-22 error.
// ---------------------------------------------------------------------------

typedef __attribute__((ext_vector_type(8))) _Float16 f16x8;
typedef __attribute__((ext_vector_type(4))) float f32x4;

__device__ __forceinline__ void split_f16(float a, unsigned short& h, unsigned short& l) {
    _Float16 ah = (_Float16)a;          // RNE
    float r = a - (float)ah;            // exact (Sterbenz)
    _Float16 al = (_Float16)r;          // RNE
    h = __builtin_bit_cast(unsigned short, ah);
    l = __builtin_bit_cast(unsigned short, al);
}

__device__ __forceinline__ unsigned enc_f32(float f) {
    unsigned u = __float_as_uint(f);
    return (u & 0x80000000u) ? ~u : (u | 0x80000000u);
}
__device__ __forceinline__ float dec_f32(unsigned e) {
    return (e & 0x80000000u) ? __uint_as_float(e & 0x7fffffffu)
                             : __uint_as_float(~e);
}
#define ENC_NEG_INF 0x007FFFFFu  // enc(-inf)

// ---------------------------------------------------------------- small utils
__global__ void k_init_gmax(unsigned* __restrict__ g) {
    g[threadIdx.x] = ENC_NEG_INF;
}

__global__ void k_count(const int* __restrict__ dst, int* __restrict__ counts, int E) {
    int e = blockIdx.x * blockDim.x + threadIdx.x;
    if (e < E) atomicAdd(&counts[dst[e]], 1);
}

__global__ void k_dinv(const int* __restrict__ counts, float* __restrict__ dinv, int N) {
    int i = blockIdx.x * blockDim.x + threadIdx.x;
    if (i < N) dinv[i] = rsqrtf((float)(counts[i] + 1));  // +1 self-loop
}

// -------------------------------------------------------------- 3-pass scan
__global__ __launch_bounds__(1024) void k_scan1(const int* __restrict__ counts,
                                                int* __restrict__ excl,
                                                int* __restrict__ bsums, int N) {
    __shared__ int sh[1024];
    int t = threadIdx.x;
    int i = blockIdx.x * 1024 + t;
    int v = (i < N) ? counts[i] : 0;
    sh[t] = v;
    __syncthreads();
    for (int off = 1; off < 1024; off <<= 1) {
        int tv = (t >= off) ? sh[t - off] : 0;
        __syncthreads();
        sh[t] += tv;
        __syncthreads();
    }
    if (i < N) excl[i] = sh[t] - v;
    if (t == 1023) bsums[blockIdx.x] = sh[1023];
}

__global__ void k_scan2(const int* __restrict__ bsums, int* __restrict__ bofs, int nb) {
    __shared__ int sh[64];
    int t = threadIdx.x;
    int v = (t < nb) ? bsums[t] : 0;
    sh[t] = v;
    __syncthreads();
    for (int off = 1; off < 64; off <<= 1) {
        int tv = (t >= off) ? sh[t - off] : 0;
        __syncthreads();
        sh[t] += tv;
        __syncthreads();
    }
    if (t < nb) bofs[t] = sh[t] - v;
}

__global__ void k_scan3(int* __restrict__ rofs, int* __restrict__ pos,
                        const int* __restrict__ bofs, int N, int E) {
    int i = blockIdx.x * blockDim.x + threadIdx.x;
    if (i < N) {
        int v = rofs[i] + bofs[i >> 10];
        rofs[i] = v;
        pos[i]  = v;
    }
    if (i == 0) rofs[N] = E;
}

__global__ void k_fill(const int* __restrict__ src, const int* __restrict__ dst,
                       int* __restrict__ pos, int* __restrict__ csr, int E) {
    int e = blockIdx.x * blockDim.x + threadIdx.x;
    if (e < E) {
        int p = atomicAdd(&pos[dst[e]], 1);
        csr[p] = src[e];
    }
}

// ------------------------------------------------------------ weight packing
// W[K][M] fp32 -> hi/lo f16 planes in MFMA B-frag order.
template <int K, int M>
__global__ void k_packw(const float* __restrict__ W, unsigned short* __restrict__ Wh,
                        unsigned short* __restrict__ Wl) {
    int c = blockIdx.x % (M / 16);
    int q = blockIdx.x / (M / 16);
    int l = threadIdx.x;  // 64
    int n = c * 16 + (l & 15);
    int k0 = q * 32 + (l >> 4) * 8;
    size_t base = ((size_t)(c * (K / 32) + q) * 64 + l) * 8;
#pragma unroll
    for (int j = 0; j < 8; ++j) {
        unsigned short h, lo;
        split_f16(W[(size_t)(k0 + j) * M + n], h, lo);
        Wh[base + j] = h;
        Wl[base + j] = lo;
    }
}

// -------------------------------------------------------------------- GEMM
// 128-row block tile, 4 waves in 2x2, wave tile 64 x (M/2). Split-f16, 3-pass.
// EPI=0: out[r][c] = sc[r] * sum_k A[r][k]*W[k][c]
// EPI=1: gmax[c] max= (A W)[r][c] + sc[c]   (encoded atomicMax)
template <int K, int M, int EPI>
__global__ __launch_bounds__(256, 2) void k_gemm(const float* __restrict__ A,
                                                 const unsigned short* __restrict__ Wh,
                                                 const unsigned short* __restrict__ Wl,
                                                 const float* __restrict__ sc,
                                                 float* __restrict__ out,
                                                 unsigned* __restrict__ gmax,
                                                 int N) {
    constexpr int CT = M / 32;  // col-tiles per wave
    constexpr int QK = K / 32;  // k chunks
    __shared__ unsigned short Ah[128 * 32], Al[128 * 32];  // frag order [tile][lane][j]
    __shared__ unsigned short Bh[M * 32], Bl[M * 32];
    __shared__ unsigned smax[64];
    const int tid = threadIdx.x;
    const int lane = tid & 63;
    const int wave = tid >> 6;
    const int wrow = wave >> 1;
    const int wcol = wave & 1;
    const int R0 = blockIdx.x * 128;

    f32x4 acc[4][CT];
#pragma unroll
    for (int rt = 0; rt < 4; ++rt)
#pragma unroll
        for (int ct = 0; ct < CT; ++ct) acc[rt][ct] = (f32x4){0.f, 0.f, 0.f, 0.f};

    for (int q = 0; q < QK; ++q) {
        const int k0 = q * 32;
        // ---- stage A: fp32 load (coalesced), split, frag-order LDS store ----
#pragma unroll
        for (int it = 0; it < 4; ++it) {
            int idx = tid + it * 256;  // 0..1023
            int r = idx >> 3;
            int kk = (idx & 7) << 2;   // 0,4,...,28
            float4 g = {0.f, 0.f, 0.f, 0.f};
            if (R0 + r < N) g = *(const float4*)&A[(size_t)(R0 + r) * K + k0 + kk];
            unsigned short h0, h1, h2, h3, l0, l1, l2, l3;
            split_f16(g.x, h0, l0);
            split_f16(g.y, h1, l1);
            split_f16(g.z, h2, l2);
            split_f16(g.w, h3, l3);
            int fo = ((r >> 4) << 9) + ((((kk >> 3) << 4) | (r & 15)) << 3) + (kk & 7);
            uint2 uh, ul;
            uh.x = (unsigned)h0 | ((unsigned)h1 << 16);
            uh.y = (unsigned)h2 | ((unsigned)h3 << 16);
            ul.x = (unsigned)l0 | ((unsigned)l1 << 16);
            ul.y = (unsigned)l2 | ((unsigned)l3 << 16);
            *(uint2*)&Ah[fo] = uh;
            *(uint2*)&Al[fo] = ul;
        }
        // ---- stage B: pre-packed, straight 16B copies ----
#pragma unroll
        for (int it = 0; it < M / 64; ++it) {
            int idx = tid + it * 256;
            int c = idx >> 6;
            int l = idx & 63;
            size_t gflat = ((size_t)(c * QK + q) * 64 + l) * 8;
            int lflat = (c * 64 + l) * 8;
            *(uint4*)&Bh[lflat] = *(const uint4*)&Wh[gflat];
            *(uint4*)&Bl[lflat] = *(const uint4*)&Wl[gflat];
        }
        __syncthreads();
        // ---- frags + 3-pass mfma ----
        f16x8 ahf[4], alf[4], bhf[CT], blf[CT];
#pragma unroll
        for (int rt = 0; rt < 4; ++rt) {
            int t = wrow * 4 + rt;
            ahf[rt] = *(const f16x8*)&Ah[(t * 64 + lane) * 8];
            alf[rt] = *(const f16x8*)&Al[(t * 64 + lane) * 8];
        }
#pragma unroll
        for (int ct = 0; ct < CT; ++ct) {
            int t = wcol * CT + ct;
            bhf[ct] = *(const f16x8*)&Bh[(t * 64 + lane) * 8];
            blf[ct] = *(const f16x8*)&Bl[(t * 64 + lane) * 8];
        }
#pragma unroll
        for (int rt = 0; rt < 4; ++rt)
#pragma unroll
            for (int ct = 0; ct < CT; ++ct) {
                acc[rt][ct] = __builtin_amdgcn_mfma_f32_16x16x32_f16(ahf[rt], bhf[ct], acc[rt][ct], 0, 0, 0);
                acc[rt][ct] = __builtin_amdgcn_mfma_f32_16x16x32_f16(ahf[rt], blf[ct], acc[rt][ct], 0, 0, 0);
                acc[rt][ct] = __builtin_amdgcn_mfma_f32_16x16x32_f16(alf[rt], bhf[ct], acc[rt][ct], 0, 0, 0);
            }
        __syncthreads();
    }

    const int quad = lane >> 4;
    if (EPI == 0) {
#pragma unroll
        for (int rt = 0; rt < 4; ++rt)
#pragma unroll
            for (int reg = 0; reg < 4; ++reg) {
                int r = R0 + wrow * 64 + rt * 16 + quad * 4 + reg;
                if (r < N) {
                    float s = sc[r];
#pragma unroll
                    for (int ct = 0; ct < CT; ++ct) {
                        int c = wcol * (CT * 16) + ct * 16 + (lane & 15);
                        out[(size_t)r * M + c] = acc[rt][ct][reg] * s;
                    }
                }
            }
    } else {
        if (tid < 64) smax[tid] = ENC_NEG_INF;
        __syncthreads();
        float cm[CT];
#pragma unroll
        for (int ct = 0; ct < CT; ++ct) cm[ct] = -INFINITY;
#pragma unroll
        for (int rt = 0; rt < 4; ++rt)
#pragma unroll
            for (int reg = 0; reg < 4; ++reg) {
                int r = R0 + wrow * 64 + rt * 16 + quad * 4 + reg;
                if (r < N) {
#pragma unroll
                    for (int ct = 0; ct < CT; ++ct) cm[ct] = fmaxf(cm[ct], acc[rt][ct][reg]);
                }
            }
#pragma unroll
        for (int ct = 0; ct < CT; ++ct) {
            float v = cm[ct];
            v = fmaxf(v, __shfl_xor(v, 16, 64));
            v = fmaxf(v, __shfl_xor(v, 32, 64));
            if (lane < 16) {
                int c = wcol * (CT * 16) + ct * 16 + lane;
                atomicMax(&smax[c], enc_f32(v + sc[c]));
            }
        }
        __syncthreads();
        if (tid < 64) atomicMax(&gmax[tid], smax[tid]);
    }
}

__global__ void k_decode(const unsigned* __restrict__ g, float* __restrict__ out) {
    out[threadIdx.x] = dec_f32(g[threadIdx.x]);
}

// ------------------------------------------------------------- aggregation
// out[d][:] = dinv[d] * (sum_{s in CSR[d]} tmp[s][:] + tmp[d][:]) + bias
// One wave per dst. dwordx4 gathers: 32 lanes cover one 512B row, the two
// wave halves take consecutive edges -> 1KB per instruction, 8 edges (4KB)
// in flight per iteration on 4 independent accumulator chains.
__global__ __launch_bounds__(256) void k_agg(const float* __restrict__ tmp,
                                             const float* __restrict__ dinv,
                                             const int* __restrict__ rofs,
                                             const int* __restrict__ csr,
                                             const float* __restrict__ bias,
                                             float* __restrict__ out, int N) {
    const int lane = threadIdx.x & 63;
    const int d = blockIdx.x * 4 + (threadIdx.x >> 6);
    if (d >= N) return;
    const int h = lane >> 5;    // which edge of the pair
    const int c4 = lane & 31;   // float4 index within row (128 floats = 32 xf4)
    const float4* __restrict__ row = (const float4*)tmp;
    int beg = rofs[d], end = rofs[d + 1];
    float ax0 = 0.f, ay0 = 0.f, az0 = 0.f, aw0 = 0.f;
    float ax1 = 0.f, ay1 = 0.f, az1 = 0.f, aw1 = 0.f;
    float ax2 = 0.f, ay2 = 0.f, az2 = 0.f, aw2 = 0.f;
    float ax3 = 0.f, ay3 = 0.f, az3 = 0.f, aw3 = 0.f;
    int e = beg;
    for (; e + 8 <= end; e += 8) {
        int s0 = csr[e + 0 + h];
        int s1 = csr[e + 2 + h];
        int s2 = csr[e + 4 + h];
        int s3 = csr[e + 6 + h];
        float4 v0 = row[(size_t)s0 * 32 + c4];
        float4 v1 = row[(size_t)s1 * 32 + c4];
        float4 v2 = row[(size_t)s2 * 32 + c4];
        float4 v3 = row[(size_t)s3 * 32 + c4];
        ax0 += v0.x; ay0 += v0.y; az0 += v0.z; aw0 += v0.w;
        ax1 += v1.x; ay1 += v1.y; az1 += v1.z; aw1 += v1.w;
        ax2 += v2.x; ay2 += v2.y; az2 += v2.z; aw2 += v2.w;
        ax3 += v3.x; ay3 += v3.y; az3 += v3.z; aw3 += v3.w;
    }
    for (; e + 2 <= end; e += 2) {
        int s = csr[e + h];
        float4 v = row[(size_t)s * 32 + c4];
        ax0 += v.x; ay0 += v.y; az0 += v.z; aw0 += v.w;
    }
    if (h == 0) {
        if (e < end) {  // odd leftover edge
            int s = csr[e];
            float4 v = row[(size_t)s * 32 + c4];
            ax1 += v.x; ay1 += v.y; az1 += v.z; aw1 += v.w;
        }
        // self-loop term
        float4 v = row[(size_t)d * 32 + c4];
        ax2 += v.x; ay2 += v.y; az2 += v.z; aw2 += v.w;
    }
    float sx = (ax0 + ax1) + (ax2 + ax3);
    float sy = (ay0 + ay1) + (ay2 + ay3);
    float sz = (az0 + az1) + (az2 + az3);
    float sw = (aw0 + aw1) + (aw2 + aw3);
    sx += __shfl_xor(sx, 32, 64);
    sy += __shfl_xor(sy, 32, 64);
    sz += __shfl_xor(sz, 32, 64);
    sw += __shfl_xor(sw, 32, 64);
    if (h == 0) {
        float di = dinv[d];
        float4 bv = ((const float4*)bias)[c4];
        float4 o;
        o.x = fmaf(di, sx, bv.x);
        o.y = fmaf(di, sy, bv.y);
        o.z = fmaf(di, sz, bv.z);
        o.w = fmaf(di, sw, bv.w);
        ((float4*)out)[(size_t)d * 32 + c4] = o;
    }
}

// ---------------------------------------------------------------------------
extern "C" void kernel_launch(void* const* d_in, const int* in_sizes, int n_in,
                              void* d_out, int out_size, void* d_ws, size_t ws_size,
                              hipStream_t stream) {
    const float* x    = (const float*)d_in[0];
    const int*   ei   = (const int*)d_in[1];  // [2,E]: row0=src, row1=dst
    const float* W0   = (const float*)d_in[3];
    const float* b0   = (const float*)d_in[4];
    const float* W1   = (const float*)d_in[5];
    const float* b1   = (const float*)d_in[6];
    const float* W2   = (const float*)d_in[7];
    const float* b2   = (const float*)d_in[8];
    const float* Wlin = (const float*)d_in[9];
    const float* blin = (const float*)d_in[10];
    float* out = (float*)d_out;

    const int N = in_sizes[2];
    const int E = in_sizes[1] / 2;
    const int* src = ei;
    const int* dst = ei + E;

    size_t off = 0;
    auto carve = [&](size_t bytes) {
        void* p = (char*)d_ws + off;
        off += (bytes + 255) & ~(size_t)255;
        return p;
    };
    int*      counts = (int*)carve((size_t)N * 4);
    int*      pos    = (int*)carve((size_t)N * 4);
    float*    dinv   = (float*)carve((size_t)N * 4);
    int*      rofs   = (int*)carve((size_t)(N + 1) * 4);
    int*      bsums  = (int*)carve(64 * 4);
    int*      bofs   = (int*)carve(64 * 4);
    int*      csr    = (int*)carve((size_t)E * 4);
    float*    tmpA   = (float*)carve((size_t)N * 128 * 4);
    float*    tmpB   = (float*)carve((size_t)N * 128 * 4);
    unsigned* gmax   = (unsigned*)carve(64 * 4);
    unsigned short* w0h = (unsigned short*)carve(256 * 128 * 2);
    unsigned short* w0l = (unsigned short*)carve(256 * 128 * 2);
    unsigned short* w1h = (unsigned short*)carve(128 * 128 * 2);
    unsigned short* w1l = (unsigned short*)carve(128 * 128 * 2);
    unsigned short* w2h = (unsigned short*)carve(128 * 128 * 2);
    unsigned short* w2l = (unsigned short*)carve(128 * 128 * 2);
    unsigned short* wlh = (unsigned short*)carve(128 * 64 * 2);
    unsigned short* wll = (unsigned short*)carve(128 * 64 * 2);
    (void)ws_size; (void)n_in; (void)out_size;

    const int nbE  = (E + 255) / 256;
    const int nbN  = (N + 255) / 256;
    const int nbS  = (N + 1023) / 1024;
    const int nbG  = (N + 127) / 128;
    const int nbAg = (N + 3) / 4;

    hipMemsetAsync(counts, 0, (size_t)N * 4, stream);
    k_init_gmax<<<1, 64, 0, stream>>>(gmax);

    // weight packing (tiny)
    k_packw<256, 128><<<(128 / 16) * (256 / 32), 64, 0, stream>>>(W0, w0h, w0l);
    k_packw<128, 128><<<(128 / 16) * (128 / 32), 64, 0, stream>>>(W1, w1h, w1l);
    k_packw<128, 128><<<(128 / 16) * (128 / 32), 64, 0, stream>>>(W2, w2h, w2l);
    k_packw<128, 64><<<(64 / 16) * (128 / 32), 64, 0, stream>>>(Wlin, wlh, wll);

    // graph structure
    k_count<<<nbE, 256, 0, stream>>>(dst, counts, E);
    k_dinv<<<nbN, 256, 0, stream>>>(counts, dinv, N);
    k_scan1<<<nbS, 1024, 0, stream>>>(counts, rofs, bsums, N);
    k_scan2<<<1, 64, 0, stream>>>(bsums, bofs, nbS);
    k_scan3<<<nbN, 256, 0, stream>>>(rofs, pos, bofs, N, E);
    k_fill<<<nbE, 256, 0, stream>>>(src, dst, pos, csr, E);

    // layer 1
    k_gemm<256, 128, 0><<<nbG, 256, 0, stream>>>(x, w0h, w0l, dinv, tmpA, nullptr, N);
    k_agg<<<nbAg, 256, 0, stream>>>(tmpA, dinv, rofs, csr, b0, tmpB, N);
    // layer 2
    k_gemm<128, 128, 0><<<nbG, 256, 0, stream>>>(tmpB, w1h, w1l, dinv, tmpA, nullptr, N);
    k_agg<<<nbAg, 256, 0, stream>>>(tmpA, dinv, rofs, csr, b1, tmpB, N);
    // layer 3
    k_gemm<128, 128, 0><<<nbG, 256, 0, stream>>>(tmpB, w2h, w2l, dinv, tmpA, nullptr, N);
    k_agg<<<nbAg, 256, 0, stream>>>(tmpA, dinv, rofs, csr, b2, tmpB, N);
    // linear + global max pool
    k_gemm<128, 64, 1><<<nbG, 256, 0, stream>>>(tmpB, wlh, wll, blin, nullptr, gmax, N);
    k_decode<<<1, 64, 0, stream>>>(gmax, out);
}

// Round 6
// 373.425 us; speedup vs baseline: 1.6243x; 1.2375x over previous
//
#include <hip/hip_runtime.h>
#include <math.h>

// ---------------------------------------------------------------------------
// GCN forward: 3x GCNConv (sym-norm, self-loops) + linear + global max pool.
// N=50000, E=800000, F=256, H=128, O=64. fp32 in/out, fp16 intermediates.
//
// R6: measured invariant — random gather costs ~10.5 cy per 128B line-touch
// per CU (R3/R4/R5 all converge). So agg cost scales with row bytes only.
// All intermediates stored fp16 [N][128] (256B rows = 2 lines/edge, was 4).
// GEMMs single-pass fp16 MFMA (error 2^-11, ~5e-5 at output vs 3.5e-4 thr).
// ---------------------------------------------------------------------------

typedef __attribute__((ext_vector_type(8))) _Float16 f16x8;
typedef __attribute__((ext_vector_type(4))) _Float16 f16x4;
typedef __attribute__((ext_vector_type(4))) float f32x4;

__device__ __forceinline__ unsigned enc_f32(float f) {
    unsigned u = __float_as_uint(f);
    return (u & 0x80000000u) ? ~u : (u | 0x80000000u);
}
__device__ __forceinline__ float dec_f32(unsigned e) {
    return (e & 0x80000000u) ? __uint_as_float(e & 0x7fffffffu)
                             : __uint_as_float(~e);
}
#define ENC_NEG_INF 0x007FFFFFu  // enc(-inf)

// ---------------------------------------------------------------- small utils
__global__ void k_init_gmax(unsigned* __restrict__ g) {
    g[threadIdx.x] = ENC_NEG_INF;
}

__global__ void k_count(const int* __restrict__ dst, int* __restrict__ counts, int E) {
    int e = blockIdx.x * blockDim.x + threadIdx.x;
    if (e < E) atomicAdd(&counts[dst[e]], 1);
}

__global__ void k_dinv(const int* __restrict__ counts, float* __restrict__ dinv, int N) {
    int i = blockIdx.x * blockDim.x + threadIdx.x;
    if (i < N) dinv[i] = rsqrtf((float)(counts[i] + 1));  // +1 self-loop
}

// -------------------------------------------------------------- 3-pass scan
__global__ __launch_bounds__(1024) void k_scan1(const int* __restrict__ counts,
                                                int* __restrict__ excl,
                                                int* __restrict__ bsums, int N) {
    __shared__ int sh[1024];
    int t = threadIdx.x;
    int i = blockIdx.x * 1024 + t;
    int v = (i < N) ? counts[i] : 0;
    sh[t] = v;
    __syncthreads();
    for (int off = 1; off < 1024; off <<= 1) {
        int tv = (t >= off) ? sh[t - off] : 0;
        __syncthreads();
        sh[t] += tv;
        __syncthreads();
    }
    if (i < N) excl[i] = sh[t] - v;
    if (t == 1023) bsums[blockIdx.x] = sh[1023];
}

__global__ void k_scan2(const int* __restrict__ bsums, int* __restrict__ bofs, int nb) {
    __shared__ int sh[64];
    int t = threadIdx.x;
    int v = (t < nb) ? bsums[t] : 0;
    sh[t] = v;
    __syncthreads();
    for (int off = 1; off < 64; off <<= 1) {
        int tv = (t >= off) ? sh[t - off] : 0;
        __syncthreads();
        sh[t] += tv;
        __syncthreads();
    }
    if (t < nb) bofs[t] = sh[t] - v;
}

__global__ void k_scan3(int* __restrict__ rofs, int* __restrict__ pos,
                        const int* __restrict__ bofs, int N, int E) {
    int i = blockIdx.x * blockDim.x + threadIdx.x;
    if (i < N) {
        int v = rofs[i] + bofs[i >> 10];
        rofs[i] = v;
        pos[i]  = v;
    }
    if (i == 0) rofs[N] = E;
}

__global__ void k_fill(const int* __restrict__ src, const int* __restrict__ dst,
                       int* __restrict__ pos, int* __restrict__ csr, int E) {
    int e = blockIdx.x * blockDim.x + threadIdx.x;
    if (e < E) {
        int p = atomicAdd(&pos[dst[e]], 1);
        csr[p] = src[e];
    }
}

// ------------------------------------------------------------ weight packing
// W[K][M] fp32 -> fp16 in MFMA B-frag order:
// flat = ((c*(K/32)+q)*64 + lane)*8 + j ; element = W[q*32+(lane>>4)*8+j][c*16+(lane&15)]
template <int K, int M>
__global__ void k_packw(const float* __restrict__ W, _Float16* __restrict__ Wp) {
    int c = blockIdx.x % (M / 16);
    int q = blockIdx.x / (M / 16);
    int l = threadIdx.x;  // 64
    int n = c * 16 + (l & 15);
    int k0 = q * 32 + (l >> 4) * 8;
    size_t base = ((size_t)(c * (K / 32) + q) * 64 + l) * 8;
#pragma unroll
    for (int j = 0; j < 8; ++j)
        Wp[base + j] = (_Float16)W[(size_t)(k0 + j) * M + n];
}

// -------------------------------------------------------------------- GEMM
// 128-row block tile, 4 waves in 2x2, wave tile 64 x (M/2). Single-pass fp16.
// ADT=0: A fp32 [N][K] (converted during staging).  ADT=1: A fp16 [N][K].
// EPI=0: out fp16[N][M], out[r][c] = (half)(sc[r] * sum_k A[r][k]*W[k][c])
// EPI=1: gmax[c] max= (A W)[r][c] + sc[c]   (encoded atomicMax)
template <int K, int M, int EPI, int ADT>
__global__ __launch_bounds__(256, 2) void k_gemm(const void* __restrict__ Av,
                                                 const _Float16* __restrict__ Wp,
                                                 const float* __restrict__ sc,
                                                 _Float16* __restrict__ out,
                                                 unsigned* __restrict__ gmax,
                                                 int N) {
    constexpr int CT = M / 32;  // col-tiles per wave
    constexpr int QK = K / 32;  // k chunks
    __shared__ _Float16 As[128 * 32];  // frag order [tile(8)][lane(64)][j(8)]
    __shared__ _Float16 Bs[M * 32];
    __shared__ unsigned smax[64];
    const int tid = threadIdx.x;
    const int lane = tid & 63;
    const int wave = tid >> 6;
    const int wrow = wave >> 1;
    const int wcol = wave & 1;
    const int R0 = blockIdx.x * 128;

    f32x4 acc[4][CT];
#pragma unroll
    for (int rt = 0; rt < 4; ++rt)
#pragma unroll
        for (int ct = 0; ct < CT; ++ct) acc[rt][ct] = (f32x4){0.f, 0.f, 0.f, 0.f};

    for (int q = 0; q < QK; ++q) {
        const int k0 = q * 32;
        if (ADT == 0) {
            const float* A = (const float*)Av;
#pragma unroll
            for (int it = 0; it < 4; ++it) {
                int idx = tid + it * 256;  // 0..1023
                int r = idx >> 3;
                int f4 = idx & 7;          // which float4 of the 32-k chunk
                float4 g = {0.f, 0.f, 0.f, 0.f};
                if (R0 + r < N) g = *(const float4*)&A[(size_t)(R0 + r) * K + k0 + f4 * 4];
                int kg = f4 >> 1, j0 = (f4 & 1) * 4;
                f16x4 h;
                h[0] = (_Float16)g.x; h[1] = (_Float16)g.y;
                h[2] = (_Float16)g.z; h[3] = (_Float16)g.w;
                *(f16x4*)&As[((r >> 4) * 512) + ((kg * 16 + (r & 15)) * 8) + j0] = h;
            }
        } else {
            const _Float16* A = (const _Float16*)Av;
#pragma unroll
            for (int it = 0; it < 2; ++it) {
                int idx = tid + it * 256;  // 0..511
                int r = idx >> 2;
                int kg = idx & 3;
                uint4 g = {0u, 0u, 0u, 0u};
                if (R0 + r < N) g = *(const uint4*)&A[(size_t)(R0 + r) * K + k0 + kg * 8];
                *(uint4*)&As[((r >> 4) * 512) + ((kg * 16 + (r & 15)) * 8)] = g;
            }
        }
        // B: pre-packed frag order, straight 16B copies
#pragma unroll
        for (int it = 0; it < M / 64; ++it) {
            int idx = tid + it * 256;
            int c = idx >> 6;
            int l = idx & 63;
            *(uint4*)&Bs[(c * 64 + l) * 8] = *(const uint4*)&Wp[((size_t)(c * QK + q) * 64 + l) * 8];
        }
        __syncthreads();
        f16x8 af[4], bf[CT];
#pragma unroll
        for (int rt = 0; rt < 4; ++rt)
            af[rt] = *(const f16x8*)&As[(wrow * 4 + rt) * 512 + lane * 8];
#pragma unroll
        for (int ct = 0; ct < CT; ++ct)
            bf[ct] = *(const f16x8*)&Bs[(wcol * CT + ct) * 512 + lane * 8];
#pragma unroll
        for (int rt = 0; rt < 4; ++rt)
#pragma unroll
            for (int ct = 0; ct < CT; ++ct)
                acc[rt][ct] = __builtin_amdgcn_mfma_f32_16x16x32_f16(af[rt], bf[ct], acc[rt][ct], 0, 0, 0);
        __syncthreads();
    }

    const int quad = lane >> 4;
    if (EPI == 0) {
#pragma unroll
        for (int rt = 0; rt < 4; ++rt)
#pragma unroll
            for (int reg = 0; reg < 4; ++reg) {
                int r = R0 + wrow * 64 + rt * 16 + quad * 4 + reg;
                if (r < N) {
                    float s = sc[r];
#pragma unroll
                    for (int ct = 0; ct < CT; ++ct) {
                        int c = wcol * (CT * 16) + ct * 16 + (lane & 15);
                        out[(size_t)r * M + c] = (_Float16)(acc[rt][ct][reg] * s);
                    }
                }
            }
    } else {
        if (tid < 64) smax[tid] = ENC_NEG_INF;
        __syncthreads();
        float cm[CT];
#pragma unroll
        for (int ct = 0; ct < CT; ++ct) cm[ct] = -INFINITY;
#pragma unroll
        for (int rt = 0; rt < 4; ++rt)
#pragma unroll
            for (int reg = 0; reg < 4; ++reg) {
                int r = R0 + wrow * 64 + rt * 16 + quad * 4 + reg;
                if (r < N) {
#pragma unroll
                    for (int ct = 0; ct < CT; ++ct) cm[ct] = fmaxf(cm[ct], acc[rt][ct][reg]);
                }
            }
#pragma unroll
        for (int ct = 0; ct < CT; ++ct) {
            float v = cm[ct];
            v = fmaxf(v, __shfl_xor(v, 16, 64));
            v = fmaxf(v, __shfl_xor(v, 32, 64));
            if (lane < 16) {
                int c = wcol * (CT * 16) + ct * 16 + lane;
                atomicMax(&smax[c], enc_f32(v + sc[c]));
            }
        }
        __syncthreads();
        if (tid < 64) atomicMax(&gmax[tid], smax[tid]);
    }
}

__global__ void k_decode(const unsigned* __restrict__ g, float* __restrict__ out) {
    out[threadIdx.x] = dec_f32(g[threadIdx.x]);
}

// ------------------------------------------------------------- aggregation
// out[d][:] = (half)( dinv[d] * (sum_{s in CSR[d]} tmp[s][:] + tmp[d][:]) + b )
// fp16 rows (256B = 2 lines/edge). One wave per dst: 4 edge slots x 16 lanes,
// 16B/lane -> 4 edges (1KB) per instruction, 4 loads in flight, fp32 accum.
__global__ __launch_bounds__(256) void k_agg(const _Float16* __restrict__ tmp,
                                             const float* __restrict__ dinv,
                                             const int* __restrict__ rofs,
                                             const int* __restrict__ csr,
                                             const float* __restrict__ bias,
                                             _Float16* __restrict__ out, int N) {
    const int lane = threadIdx.x & 63;
    const int d = blockIdx.x * 4 + (threadIdx.x >> 6);
    if (d >= N) return;
    const int eh = lane >> 4;   // edge slot
    const int fl = lane & 15;   // feature group (8 halfs)
    const int beg = rofs[d], end = rofs[d + 1];
    float a[8];
#pragma unroll
    for (int j = 0; j < 8; ++j) a[j] = 0.f;

    int e = beg;
    for (; e + 16 <= end; e += 16) {
        int s0 = csr[e + eh];
        int s1 = csr[e + 4 + eh];
        int s2 = csr[e + 8 + eh];
        int s3 = csr[e + 12 + eh];
        f16x8 v0 = *(const f16x8*)&tmp[(size_t)s0 * 128 + fl * 8];
        f16x8 v1 = *(const f16x8*)&tmp[(size_t)s1 * 128 + fl * 8];
        f16x8 v2 = *(const f16x8*)&tmp[(size_t)s2 * 128 + fl * 8];
        f16x8 v3 = *(const f16x8*)&tmp[(size_t)s3 * 128 + fl * 8];
#pragma unroll
        for (int j = 0; j < 8; ++j) a[j] += (float)v0[j];
#pragma unroll
        for (int j = 0; j < 8; ++j) a[j] += (float)v1[j];
#pragma unroll
        for (int j = 0; j < 8; ++j) a[j] += (float)v2[j];
#pragma unroll
        for (int j = 0; j < 8; ++j) a[j] += (float)v3[j];
    }
    for (; e + 4 <= end; e += 4) {
        int s = csr[e + eh];
        f16x8 v = *(const f16x8*)&tmp[(size_t)s * 128 + fl * 8];
#pragma unroll
        for (int j = 0; j < 8; ++j) a[j] += (float)v[j];
    }
    if (eh < end - e) {
        int s = csr[e + eh];
        f16x8 v = *(const f16x8*)&tmp[(size_t)s * 128 + fl * 8];
#pragma unroll
        for (int j = 0; j < 8; ++j) a[j] += (float)v[j];
    }
    if (eh == 3) {  // self-loop term
        f16x8 v = *(const f16x8*)&tmp[(size_t)d * 128 + fl * 8];
#pragma unroll
        for (int j = 0; j < 8; ++j) a[j] += (float)v[j];
    }
    // combine the 4 slots
#pragma unroll
    for (int j = 0; j < 8; ++j) {
        a[j] += __shfl_xor(a[j], 16, 64);
        a[j] += __shfl_xor(a[j], 32, 64);
    }
    if (eh == 0) {
        float di = dinv[d];
        float4 b0 = *(const float4*)&bias[fl * 8];
        float4 b1 = *(const float4*)&bias[fl * 8 + 4];
        f16x8 o;
        o[0] = (_Float16)fmaf(di, a[0], b0.x);
        o[1] = (_Float16)fmaf(di, a[1], b0.y);
        o[2] = (_Float16)fmaf(di, a[2], b0.z);
        o[3] = (_Float16)fmaf(di, a[3], b0.w);
        o[4] = (_Float16)fmaf(di, a[4], b1.x);
        o[5] = (_Float16)fmaf(di, a[5], b1.y);
        o[6] = (_Float16)fmaf(di, a[6], b1.z);
        o[7] = (_Float16)fmaf(di, a[7], b1.w);
        *(f16x8*)&out[(size_t)d * 128 + fl * 8] = o;
    }
}

// ---------------------------------------------------------------------------
extern "C" void kernel_launch(void* const* d_in, const int* in_sizes, int n_in,
                              void* d_out, int out_size, void* d_ws, size_t ws_size,
                              hipStream_t stream) {
    const float* x    = (const float*)d_in[0];
    const int*   ei   = (const int*)d_in[1];  // [2,E]: row0=src, row1=dst
    const float* W0   = (const float*)d_in[3];
    const float* b0   = (const float*)d_in[4];
    const float* W1   = (const float*)d_in[5];
    const float* b1   = (const float*)d_in[6];
    const float* W2   = (const float*)d_in[7];
    const float* b2   = (const float*)d_in[8];
    const float* Wlin = (const float*)d_in[9];
    const float* blin = (const float*)d_in[10];
    float* out = (float*)d_out;

    const int N = in_sizes[2];
    const int E = in_sizes[1] / 2;
    const int* src = ei;
    const int* dst = ei + E;

    size_t off = 0;
    auto carve = [&](size_t bytes) {
        void* p = (char*)d_ws + off;
        off += (bytes + 255) & ~(size_t)255;
        return p;
    };
    int*       counts = (int*)carve((size_t)N * 4);
    int*       pos    = (int*)carve((size_t)N * 4);
    float*     dinv   = (float*)carve((size_t)N * 4);
    int*       rofs   = (int*)carve((size_t)(N + 1) * 4);
    int*       bsums  = (int*)carve(64 * 4);
    int*       bofs   = (int*)carve(64 * 4);
    int*       csr    = (int*)carve((size_t)E * 4);
    _Float16*  tmpA   = (_Float16*)carve((size_t)N * 128 * 2);
    _Float16*  tmpB   = (_Float16*)carve((size_t)N * 128 * 2);
    unsigned*  gmax   = (unsigned*)carve(64 * 4);
    _Float16*  w0p    = (_Float16*)carve(256 * 128 * 2);
    _Float16*  w1p    = (_Float16*)carve(128 * 128 * 2);
    _Float16*  w2p    = (_Float16*)carve(128 * 128 * 2);
    _Float16*  wlp    = (_Float16*)carve(128 * 64 * 2);
    (void)ws_size; (void)n_in; (void)out_size;

    const int nbE  = (E + 255) / 256;
    const int nbN  = (N + 255) / 256;
    const int nbS  = (N + 1023) / 1024;
    const int nbG  = (N + 127) / 128;
    const int nbAg = (N + 3) / 4;

    hipMemsetAsync(counts, 0, (size_t)N * 4, stream);
    k_init_gmax<<<1, 64, 0, stream>>>(gmax);

    // weight packing (tiny)
    k_packw<256, 128><<<(128 / 16) * (256 / 32), 64, 0, stream>>>(W0, w0p);
    k_packw<128, 128><<<(128 / 16) * (128 / 32), 64, 0, stream>>>(W1, w1p);
    k_packw<128, 128><<<(128 / 16) * (128 / 32), 64, 0, stream>>>(W2, w2p);
    k_packw<128, 64><<<(64 / 16) * (128 / 32), 64, 0, stream>>>(Wlin, wlp);

    // graph structure
    k_count<<<nbE, 256, 0, stream>>>(dst, counts, E);
    k_dinv<<<nbN, 256, 0, stream>>>(counts, dinv, N);
    k_scan1<<<nbS, 1024, 0, stream>>>(counts, rofs, bsums, N);
    k_scan2<<<1, 64, 0, stream>>>(bsums, bofs, nbS);
    k_scan3<<<nbN, 256, 0, stream>>>(rofs, pos, bofs, N, E);
    k_fill<<<nbE, 256, 0, stream>>>(src, dst, pos, csr, E);

    // layer 1 (A = fp32 x)
    k_gemm<256, 128, 0, 0><<<nbG, 256, 0, stream>>>(x, w0p, dinv, tmpA, nullptr, N);
    k_agg<<<nbAg, 256, 0, stream>>>(tmpA, dinv, rofs, csr, b0, tmpB, N);
    // layer 2
    k_gemm<128, 128, 0, 1><<<nbG, 256, 0, stream>>>(tmpB, w1p, dinv, tmpA, nullptr, N);
    k_agg<<<nbAg, 256, 0, stream>>>(tmpA, dinv, rofs, csr, b1, tmpB, N);
    // layer 3
    k_gemm<128, 128, 0, 1><<<nbG, 256, 0, stream>>>(tmpB, w2p, dinv, tmpA, nullptr, N);
    k_agg<<<nbAg, 256, 0, stream>>>(tmpA, dinv, rofs, csr, b2, tmpB, N);
    // linear + global max pool
    k_gemm<128, 64, 1, 1><<<nbG, 256, 0, stream>>>(tmpB, wlp, blin, nullptr, gmax, N);
    k_decode<<<1, 64, 0, stream>>>(gmax, out);
}

// Round 7
// 312.433 us; speedup vs baseline: 1.9414x; 1.1952x over previous
//
#include <hip/hip_runtime.h>
#include <math.h>

// ---------------------------------------------------------------------------
// GCN forward: 3x GCNConv (sym-norm, self-loops) + linear + global max pool.
// N=50000, E=800000, F=256, H=128, O=64. fp32 in/out, fp16 intermediates.
//
// R7: graph build rewritten atomic-free (global atomics were ~85us at
// ~13cy/divergent-txn): LDS multisplit into 128-dst buckets + per-bucket LDS
// counting sort -> dst-sorted csr (u16 src; requires N<=65536), rofs, dinv.
// GEMMs single-pass fp16 MFMA; agg gathers fp16 256B rows (2 lines/edge).
// ---------------------------------------------------------------------------

typedef __attribute__((ext_vector_type(8))) _Float16 f16x8;
typedef __attribute__((ext_vector_type(4))) _Float16 f16x4;
typedef __attribute__((ext_vector_type(4))) float f32x4;

__device__ __forceinline__ unsigned enc_f32(float f) {
    unsigned u = __float_as_uint(f);
    return (u & 0x80000000u) ? ~u : (u | 0x80000000u);
}
__device__ __forceinline__ float dec_f32(unsigned e) {
    return (e & 0x80000000u) ? __uint_as_float(e & 0x7fffffffu)
                             : __uint_as_float(~e);
}
#define ENC_NEG_INF 0x007FFFFFu  // enc(-inf)

__global__ void k_init_gmax(unsigned* __restrict__ g) {
    g[threadIdx.x] = ENC_NEG_INF;
}

// ------------------------------------------------------- graph build, pass A
// per-block histogram of dst>>7 over this block's edge chunk -> T[bucket][blk]
__global__ __launch_bounds__(256) void k_hist(const int* __restrict__ dst,
                                              int* __restrict__ T,
                                              int E, int NB, int chunk) {
    __shared__ int hist[512];
    for (int i = threadIdx.x; i < 512; i += 256) hist[i] = 0;
    __syncthreads();
    const int lo = blockIdx.x * chunk, hi = min(E, lo + chunk);
    for (int e = lo + threadIdx.x; e < hi; e += 256)
        atomicAdd(&hist[dst[e] >> 7], 1);
    __syncthreads();
    for (int b = threadIdx.x; b < NB; b += 256)
        T[b * 256 + blockIdx.x] = hist[b];
}

// ------------------------------------------------------------- 3-pass scan
__global__ __launch_bounds__(1024) void k_scan1(const int* __restrict__ in,
                                                int* __restrict__ excl,
                                                int* __restrict__ bsums, int L) {
    __shared__ int sh[1024];
    int t = threadIdx.x;
    int i = blockIdx.x * 1024 + t;
    int v = (i < L) ? in[i] : 0;
    sh[t] = v;
    __syncthreads();
    for (int off = 1; off < 1024; off <<= 1) {
        int tv = (t >= off) ? sh[t - off] : 0;
        __syncthreads();
        sh[t] += tv;
        __syncthreads();
    }
    if (i < L) excl[i] = sh[t] - v;
    if (t == 1023) bsums[blockIdx.x] = sh[1023];
}

__global__ __launch_bounds__(1024) void k_scan2(const int* __restrict__ bsums,
                                                int* __restrict__ bofs, int nb) {
    __shared__ int sh[1024];
    int t = threadIdx.x;
    int v = (t < nb) ? bsums[t] : 0;
    sh[t] = v;
    __syncthreads();
    for (int off = 1; off < 1024; off <<= 1) {
        int tv = (t >= off) ? sh[t - off] : 0;
        __syncthreads();
        sh[t] += tv;
        __syncthreads();
    }
    if (t < nb) bofs[t] = sh[t] - v;
}

__global__ void k_scan3(int* __restrict__ arr, const int* __restrict__ bofs, int L) {
    int i = blockIdx.x * blockDim.x + threadIdx.x;
    if (i < L) arr[i] += bofs[i >> 10];
}

// ------------------------------------------------------- graph build, pass B
// multisplit: group this block's chunk by bucket (LDS scatter, coalesced-run
// global write at precomputed offsets T2[bucket][blk]). Packed edge =
// (dst<<16)|src (requires N<=65536).
#define PBT 4096
__global__ __launch_bounds__(256) void k_part(const int* __restrict__ src,
                                              const int* __restrict__ dst,
                                              const int* __restrict__ T2,
                                              unsigned* __restrict__ eb,
                                              int E, int NB, int chunk) {
    __shared__ int hist[512], lexc[512], pos[512], wpos[512];
    __shared__ unsigned sorted[PBT];
    const int t = threadIdx.x;
    const int blk = blockIdx.x;
    const int lo = blk * chunk, hi = min(E, lo + chunk);
    for (int i = t; i < NB; i += 256) wpos[i] = T2[i * 256 + blk];
    __syncthreads();
    for (int tlo = lo; tlo < hi; tlo += PBT) {
        const int thi = min(hi, tlo + PBT);
        const int sz = thi - tlo;
        for (int i = t; i < 512; i += 256) hist[i] = 0;
        __syncthreads();
        for (int e = tlo + t; e < thi; e += 256)
            atomicAdd(&hist[dst[e] >> 7], 1);
        __syncthreads();
        // exclusive scan over 512 buckets, 2 elems/thread Hillis-Steele
        const int i0 = t, i1 = t + 256;
        const int o0 = hist[i0], o1 = hist[i1];
        for (int off = 1; off < 512; off <<= 1) {
            int v0 = (i0 >= off) ? hist[i0 - off] : 0;
            int v1 = (i1 >= off) ? hist[i1 - off] : 0;
            __syncthreads();
            hist[i0] += v0;
            hist[i1] += v1;
            __syncthreads();
        }
        lexc[i0] = hist[i0] - o0; pos[i0] = hist[i0] - o0;
        lexc[i1] = hist[i1] - o1; pos[i1] = hist[i1] - o1;
        __syncthreads();
        for (int e = tlo + t; e < thi; e += 256) {
            int d = dst[e];
            int p = atomicAdd(&pos[d >> 7], 1);
            sorted[p] = ((unsigned)d << 16) | (unsigned)src[e];
        }
        __syncthreads();
        for (int i = t; i < sz; i += 256) {
            unsigned x = sorted[i];
            int b = (int)(x >> 23);
            eb[wpos[b] + (i - lexc[b])] = x;
        }
        __syncthreads();
        wpos[i0] += o0;
        wpos[i1] += o1;
        __syncthreads();
    }
}

// ------------------------------------------------------- graph build, pass C
// one block per bucket: LDS counting sort of the bucket's edges -> csr (u16
// src), rofs, dinv. Bucket b covers dsts [b*128, b*128+128).
#define PCT 6144
__global__ __launch_bounds__(256) void k_build(const unsigned* __restrict__ eb,
                                               const int* __restrict__ T2,
                                               unsigned short* __restrict__ csr,
                                               int* __restrict__ rofs,
                                               float* __restrict__ dinv,
                                               int N, int E, int NB) {
    __shared__ int hist[128], lofs[128], pos[128];
    __shared__ unsigned short ssrc[PCT];
    const int t = threadIdx.x;
    const int b = blockIdx.x;
    const int glo = T2[b * 256];
    const int ghi = (b + 1 < NB) ? T2[(b + 1) * 256] : E;
    const int sz = ghi - glo;
    if (t < 128) hist[t] = 0;
    __syncthreads();
    for (int i = t; i < sz; i += 256)
        atomicAdd(&hist[(eb[glo + i] >> 16) & 127], 1);
    __syncthreads();
    const int o = (t < 128) ? hist[t] : 0;
    for (int off = 1; off < 128; off <<= 1) {
        int v = (t < 128 && t >= off) ? hist[t - off] : 0;
        __syncthreads();
        if (t < 128) hist[t] += v;
        __syncthreads();
    }
    if (t < 128) {
        int ex = hist[t] - o;
        lofs[t] = ex;
        pos[t] = ex;
        int d = b * 128 + t;
        if (d < N) {
            rofs[d] = glo + ex;
            dinv[d] = rsqrtf((float)(o + 1));  // +1 self-loop
        }
    }
    __syncthreads();
    if (sz <= PCT) {
        for (int i = t; i < sz; i += 256) {
            unsigned x = eb[glo + i];
            int p = atomicAdd(&pos[(x >> 16) & 127], 1);
            ssrc[p] = (unsigned short)(x & 0xFFFFu);
        }
        __syncthreads();
        for (int i = t; i < sz; i += 256) csr[glo + i] = ssrc[i];
    } else {  // overflow fallback (never taken at this size), still correct
        for (int i = t; i < sz; i += 256) {
            unsigned x = eb[glo + i];
            int p = atomicAdd(&pos[(x >> 16) & 127], 1);
            csr[glo + p] = (unsigned short)(x & 0xFFFFu);
        }
    }
    if (b == 0 && t == 0) rofs[N] = E;
}

// ------------------------------------------------------------ weight packing
// W[K][M] fp32 -> fp16 in MFMA B-frag order.
template <int K, int M>
__global__ void k_packw(const float* __restrict__ W, _Float16* __restrict__ Wp) {
    int c = blockIdx.x % (M / 16);
    int q = blockIdx.x / (M / 16);
    int l = threadIdx.x;  // 64
    int n = c * 16 + (l & 15);
    int k0 = q * 32 + (l >> 4) * 8;
    size_t base = ((size_t)(c * (K / 32) + q) * 64 + l) * 8;
#pragma unroll
    for (int j = 0; j < 8; ++j)
        Wp[base + j] = (_Float16)W[(size_t)(k0 + j) * M + n];
}

// -------------------------------------------------------------------- GEMM
// 128-row block tile, 4 waves in 2x2, wave tile 64 x (M/2). Single-pass fp16.
// ADT=0: A fp32 [N][K] (converted during staging).  ADT=1: A fp16 [N][K].
// EPI=0: out fp16[N][M] = (half)(sc[r] * A W).  EPI=1: global max pool.
template <int K, int M, int EPI, int ADT>
__global__ __launch_bounds__(256, 2) void k_gemm(const void* __restrict__ Av,
                                                 const _Float16* __restrict__ Wp,
                                                 const float* __restrict__ sc,
                                                 _Float16* __restrict__ out,
                                                 unsigned* __restrict__ gmax,
                                                 int N) {
    constexpr int CT = M / 32;
    constexpr int QK = K / 32;
    __shared__ _Float16 As[128 * 32];
    __shared__ _Float16 Bs[M * 32];
    __shared__ unsigned smax[64];
    const int tid = threadIdx.x;
    const int lane = tid & 63;
    const int wave = tid >> 6;
    const int wrow = wave >> 1;
    const int wcol = wave & 1;
    const int R0 = blockIdx.x * 128;

    f32x4 acc[4][CT];
#pragma unroll
    for (int rt = 0; rt < 4; ++rt)
#pragma unroll
        for (int ct = 0; ct < CT; ++ct) acc[rt][ct] = (f32x4){0.f, 0.f, 0.f, 0.f};

    for (int q = 0; q < QK; ++q) {
        const int k0 = q * 32;
        if (ADT == 0) {
            const float* A = (const float*)Av;
#pragma unroll
            for (int it = 0; it < 4; ++it) {
                int idx = tid + it * 256;
                int r = idx >> 3;
                int f4 = idx & 7;
                float4 g = {0.f, 0.f, 0.f, 0.f};
                if (R0 + r < N) g = *(const float4*)&A[(size_t)(R0 + r) * K + k0 + f4 * 4];
                int kg = f4 >> 1, j0 = (f4 & 1) * 4;
                f16x4 h;
                h[0] = (_Float16)g.x; h[1] = (_Float16)g.y;
                h[2] = (_Float16)g.z; h[3] = (_Float16)g.w;
                *(f16x4*)&As[((r >> 4) * 512) + ((kg * 16 + (r & 15)) * 8) + j0] = h;
            }
        } else {
            const _Float16* A = (const _Float16*)Av;
#pragma unroll
            for (int it = 0; it < 2; ++it) {
                int idx = tid + it * 256;
                int r = idx >> 2;
                int kg = idx & 3;
                uint4 g = {0u, 0u, 0u, 0u};
                if (R0 + r < N) g = *(const uint4*)&A[(size_t)(R0 + r) * K + k0 + kg * 8];
                *(uint4*)&As[((r >> 4) * 512) + ((kg * 16 + (r & 15)) * 8)] = g;
            }
        }
#pragma unroll
        for (int it = 0; it < M / 64; ++it) {
            int idx = tid + it * 256;
            int c = idx >> 6;
            int l = idx & 63;
            *(uint4*)&Bs[(c * 64 + l) * 8] = *(const uint4*)&Wp[((size_t)(c * QK + q) * 64 + l) * 8];
        }
        __syncthreads();
        f16x8 af[4], bf[CT];
#pragma unroll
        for (int rt = 0; rt < 4; ++rt)
            af[rt] = *(const f16x8*)&As[(wrow * 4 + rt) * 512 + lane * 8];
#pragma unroll
        for (int ct = 0; ct < CT; ++ct)
            bf[ct] = *(const f16x8*)&Bs[(wcol * CT + ct) * 512 + lane * 8];
#pragma unroll
        for (int rt = 0; rt < 4; ++rt)
#pragma unroll
            for (int ct = 0; ct < CT; ++ct)
                acc[rt][ct] = __builtin_amdgcn_mfma_f32_16x16x32_f16(af[rt], bf[ct], acc[rt][ct], 0, 0, 0);
        __syncthreads();
    }

    const int quad = lane >> 4;
    if (EPI == 0) {
#pragma unroll
        for (int rt = 0; rt < 4; ++rt)
#pragma unroll
            for (int reg = 0; reg < 4; ++reg) {
                int r = R0 + wrow * 64 + rt * 16 + quad * 4 + reg;
                if (r < N) {
                    float s = sc[r];
#pragma unroll
                    for (int ct = 0; ct < CT; ++ct) {
                        int c = wcol * (CT * 16) + ct * 16 + (lane & 15);
                        out[(size_t)r * M + c] = (_Float16)(acc[rt][ct][reg] * s);
                    }
                }
            }
    } else {
        if (tid < 64) smax[tid] = ENC_NEG_INF;
        __syncthreads();
        float cm[CT];
#pragma unroll
        for (int ct = 0; ct < CT; ++ct) cm[ct] = -INFINITY;
#pragma unroll
        for (int rt = 0; rt < 4; ++rt)
#pragma unroll
            for (int reg = 0; reg < 4; ++reg) {
                int r = R0 + wrow * 64 + rt * 16 + quad * 4 + reg;
                if (r < N) {
#pragma unroll
                    for (int ct = 0; ct < CT; ++ct) cm[ct] = fmaxf(cm[ct], acc[rt][ct][reg]);
                }
            }
#pragma unroll
        for (int ct = 0; ct < CT; ++ct) {
            float v = cm[ct];
            v = fmaxf(v, __shfl_xor(v, 16, 64));
            v = fmaxf(v, __shfl_xor(v, 32, 64));
            if (lane < 16) {
                int c = wcol * (CT * 16) + ct * 16 + lane;
                atomicMax(&smax[c], enc_f32(v + sc[c]));
            }
        }
        __syncthreads();
        if (tid < 64) atomicMax(&gmax[tid], smax[tid]);
    }
}

__global__ void k_decode(const unsigned* __restrict__ g, float* __restrict__ out) {
    out[threadIdx.x] = dec_f32(g[threadIdx.x]);
}

// ------------------------------------------------------------- aggregation
// fp16 rows (256B = 2 lines/edge). One wave per dst: 4 edge slots x 16 lanes,
// 16B/lane -> 4 edges (1KB) per instruction, fp32 accum, shfl combine.
__global__ __launch_bounds__(256) void k_agg(const _Float16* __restrict__ tmp,
                                             const float* __restrict__ dinv,
                                             const int* __restrict__ rofs,
                                             const unsigned short* __restrict__ csr,
                                             const float* __restrict__ bias,
                                             _Float16* __restrict__ out, int N) {
    const int lane = threadIdx.x & 63;
    const int d = blockIdx.x * 4 + (threadIdx.x >> 6);
    if (d >= N) return;
    const int eh = lane >> 4;
    const int fl = lane & 15;
    const int beg = rofs[d], end = rofs[d + 1];
    float a[8];
#pragma unroll
    for (int j = 0; j < 8; ++j) a[j] = 0.f;

    int e = beg;
    for (; e + 16 <= end; e += 16) {
        int s0 = csr[e + eh];
        int s1 = csr[e + 4 + eh];
        int s2 = csr[e + 8 + eh];
        int s3 = csr[e + 12 + eh];
        f16x8 v0 = *(const f16x8*)&tmp[(size_t)s0 * 128 + fl * 8];
        f16x8 v1 = *(const f16x8*)&tmp[(size_t)s1 * 128 + fl * 8];
        f16x8 v2 = *(const f16x8*)&tmp[(size_t)s2 * 128 + fl * 8];
        f16x8 v3 = *(const f16x8*)&tmp[(size_t)s3 * 128 + fl * 8];
#pragma unroll
        for (int j = 0; j < 8; ++j) a[j] += (float)v0[j];
#pragma unroll
        for (int j = 0; j < 8; ++j) a[j] += (float)v1[j];
#pragma unroll
        for (int j = 0; j < 8; ++j) a[j] += (float)v2[j];
#pragma unroll
        for (int j = 0; j < 8; ++j) a[j] += (float)v3[j];
    }
    for (; e + 4 <= end; e += 4) {
        int s = csr[e + eh];
        f16x8 v = *(const f16x8*)&tmp[(size_t)s * 128 + fl * 8];
#pragma unroll
        for (int j = 0; j < 8; ++j) a[j] += (float)v[j];
    }
    if (eh < end - e) {
        int s = csr[e + eh];
        f16x8 v = *(const f16x8*)&tmp[(size_t)s * 128 + fl * 8];
#pragma unroll
        for (int j = 0; j < 8; ++j) a[j] += (float)v[j];
    }
    if (eh == 3) {  // self-loop
        f16x8 v = *(const f16x8*)&tmp[(size_t)d * 128 + fl * 8];
#pragma unroll
        for (int j = 0; j < 8; ++j) a[j] += (float)v[j];
    }
#pragma unroll
    for (int j = 0; j < 8; ++j) {
        a[j] += __shfl_xor(a[j], 16, 64);
        a[j] += __shfl_xor(a[j], 32, 64);
    }
    if (eh == 0) {
        float di = dinv[d];
        float4 b0 = *(const float4*)&bias[fl * 8];
        float4 b1 = *(const float4*)&bias[fl * 8 + 4];
        f16x8 o;
        o[0] = (_Float16)fmaf(di, a[0], b0.x);
        o[1] = (_Float16)fmaf(di, a[1], b0.y);
        o[2] = (_Float16)fmaf(di, a[2], b0.z);
        o[3] = (_Float16)fmaf(di, a[3], b0.w);
        o[4] = (_Float16)fmaf(di, a[4], b1.x);
        o[5] = (_Float16)fmaf(di, a[5], b1.y);
        o[6] = (_Float16)fmaf(di, a[6], b1.z);
        o[7] = (_Float16)fmaf(di, a[7], b1.w);
        *(f16x8*)&out[(size_t)d * 128 + fl * 8] = o;
    }
}

// ---------------------------------------------------------------------------
extern "C" void kernel_launch(void* const* d_in, const int* in_sizes, int n_in,
                              void* d_out, int out_size, void* d_ws, size_t ws_size,
                              hipStream_t stream) {
    const float* x    = (const float*)d_in[0];
    const int*   ei   = (const int*)d_in[1];  // [2,E]: row0=src, row1=dst
    const float* W0   = (const float*)d_in[3];
    const float* b0   = (const float*)d_in[4];
    const float* W1   = (const float*)d_in[5];
    const float* b1   = (const float*)d_in[6];
    const float* W2   = (const float*)d_in[7];
    const float* b2   = (const float*)d_in[8];
    const float* Wlin = (const float*)d_in[9];
    const float* blin = (const float*)d_in[10];
    float* out = (float*)d_out;

    const int N = in_sizes[2];
    const int E = in_sizes[1] / 2;
    const int* src = ei;
    const int* dst = ei + E;

    size_t off = 0;
    auto carve = [&](size_t bytes) {
        void* p = (char*)d_ws + off;
        off += (bytes + 255) & ~(size_t)255;
        return p;
    };
    const int NB    = (N + 127) / 128;    // dst buckets (<=512 for N<=65536)
    const int L     = NB * 256;           // table size
    const int chunk = (E + 255) / 256;    // edges per k_hist/k_part block

    float*          dinv = (float*)carve((size_t)N * 4);
    int*            rofs = (int*)carve((size_t)(N + 1) * 4);
    int*            T    = (int*)carve((size_t)L * 4);
    int*            T2   = (int*)carve((size_t)L * 4);
    int*            bsums = (int*)carve(1024 * 4);
    int*            bofs  = (int*)carve(1024 * 4);
    unsigned*       eb   = (unsigned*)carve((size_t)E * 4);
    unsigned short* csr  = (unsigned short*)carve((size_t)E * 2);
    _Float16*       tmpA = (_Float16*)carve((size_t)N * 128 * 2);
    _Float16*       tmpB = (_Float16*)carve((size_t)N * 128 * 2);
    unsigned*       gmax = (unsigned*)carve(64 * 4);
    _Float16*       w0p  = (_Float16*)carve(256 * 128 * 2);
    _Float16*       w1p  = (_Float16*)carve(128 * 128 * 2);
    _Float16*       w2p  = (_Float16*)carve(128 * 128 * 2);
    _Float16*       wlp  = (_Float16*)carve(128 * 64 * 2);
    (void)ws_size; (void)n_in; (void)out_size;

    const int nbG  = (N + 127) / 128;
    const int nbAg = (N + 3) / 4;
    const int nbS  = (L + 1023) / 1024;   // <=128 for N<=65536

    k_init_gmax<<<1, 64, 0, stream>>>(gmax);

    // weight packing (tiny)
    k_packw<256, 128><<<(128 / 16) * (256 / 32), 64, 0, stream>>>(W0, w0p);
    k_packw<128, 128><<<(128 / 16) * (128 / 32), 64, 0, stream>>>(W1, w1p);
    k_packw<128, 128><<<(128 / 16) * (128 / 32), 64, 0, stream>>>(W2, w2p);
    k_packw<128, 64><<<(64 / 16) * (128 / 32), 64, 0, stream>>>(Wlin, wlp);

    // graph build: hist -> scan(T) -> partition -> per-bucket counting sort
    k_hist<<<256, 256, 0, stream>>>(dst, T, E, NB, chunk);
    k_scan1<<<nbS, 1024, 0, stream>>>(T, T2, bsums, L);
    k_scan2<<<1, 1024, 0, stream>>>(bsums, bofs, nbS);
    k_scan3<<<(L + 255) / 256, 256, 0, stream>>>(T2, bofs, L);
    k_part<<<256, 256, 0, stream>>>(src, dst, T2, eb, E, NB, chunk);
    k_build<<<NB, 256, 0, stream>>>(eb, T2, csr, rofs, dinv, N, E, NB);

    // layer 1 (A = fp32 x)
    k_gemm<256, 128, 0, 0><<<nbG, 256, 0, stream>>>(x, w0p, dinv, tmpA, nullptr, N);
    k_agg<<<nbAg, 256, 0, stream>>>(tmpA, dinv, rofs, csr, b0, tmpB, N);
    // layer 2
    k_gemm<128, 128, 0, 1><<<nbG, 256, 0, stream>>>(tmpB, w1p, dinv, tmpA, nullptr, N);
    k_agg<<<nbAg, 256, 0, stream>>>(tmpA, dinv, rofs, csr, b1, tmpB, N);
    // layer 3
    k_gemm<128, 128, 0, 1><<<nbG, 256, 0, stream>>>(tmpB, w2p, dinv, tmpA, nullptr, N);
    k_agg<<<nbAg, 256, 0, stream>>>(tmpA, dinv, rofs, csr, b2, tmpB, N);
    // linear + global max pool
    k_gemm<128, 64, 1, 1><<<nbG, 256, 0, stream>>>(tmpB, wlp, blin, nullptr, gmax, N);
    k_decode<<<1, 64, 0, stream>>>(gmax, out);
}

// Round 8
// 303.241 us; speedup vs baseline: 2.0003x; 1.0303x over previous
//
#include <hip/hip_runtime.h>
#include <math.h>

// ---------------------------------------------------------------------------
// GCN forward: 3x GCNConv (sym-norm, self-loops) + linear + global max pool.
// N=50000, E=800000, F=256, H=128, O=64. fp32 in/out, fp16 intermediates.
//
// R8: GEMMs restructured — 96-row tiles (521 blocks = 2.04/CU: two full
// rounds, no tail), full-K LDS staging for K=128 (1 barrier, 48 MFMA/wave),
// KB=128 two-stage for K=256. XOR-swizzled A-frag LDS (conflict-free).
// Graph build: LDS multisplit + per-bucket counting sort (atomic-free).
// Agg: fp16 256B-row gathers, 4 edges (1KB) per instruction.
// ---------------------------------------------------------------------------

typedef __attribute__((ext_vector_type(8))) _Float16 f16x8;
typedef __attribute__((ext_vector_type(4))) _Float16 f16x4;
typedef __attribute__((ext_vector_type(4))) float f32x4;

__device__ __forceinline__ unsigned enc_f32(float f) {
    unsigned u = __float_as_uint(f);
    return (u & 0x80000000u) ? ~u : (u | 0x80000000u);
}
__device__ __forceinline__ float dec_f32(unsigned e) {
    return (e & 0x80000000u) ? __uint_as_float(e & 0x7fffffffu)
                             : __uint_as_float(~e);
}
#define ENC_NEG_INF 0x007FFFFFu  // enc(-inf)

// ------------------------------------------------------- graph build, pass A
__global__ __launch_bounds__(256) void k_hist(const int* __restrict__ dst,
                                              int* __restrict__ T,
                                              int E, int NB, int chunk) {
    __shared__ int hist[512];
    for (int i = threadIdx.x; i < 512; i += 256) hist[i] = 0;
    __syncthreads();
    const int lo = blockIdx.x * chunk, hi = min(E, lo + chunk);
    for (int e = lo + threadIdx.x; e < hi; e += 256)
        atomicAdd(&hist[dst[e] >> 7], 1);
    __syncthreads();
    for (int b = threadIdx.x; b < NB; b += 256)
        T[b * 256 + blockIdx.x] = hist[b];
}

// ------------------------------------------------------------- 3-pass scan
__global__ __launch_bounds__(1024) void k_scan1(const int* __restrict__ in,
                                                int* __restrict__ excl,
                                                int* __restrict__ bsums, int L) {
    __shared__ int sh[1024];
    int t = threadIdx.x;
    int i = blockIdx.x * 1024 + t;
    int v = (i < L) ? in[i] : 0;
    sh[t] = v;
    __syncthreads();
    for (int off = 1; off < 1024; off <<= 1) {
        int tv = (t >= off) ? sh[t - off] : 0;
        __syncthreads();
        sh[t] += tv;
        __syncthreads();
    }
    if (i < L) excl[i] = sh[t] - v;
    if (t == 1023) bsums[blockIdx.x] = sh[1023];
}

__global__ __launch_bounds__(1024) void k_scan2(const int* __restrict__ bsums,
                                                int* __restrict__ bofs, int nb) {
    __shared__ int sh[1024];
    int t = threadIdx.x;
    int v = (t < nb) ? bsums[t] : 0;
    sh[t] = v;
    __syncthreads();
    for (int off = 1; off < 1024; off <<= 1) {
        int tv = (t >= off) ? sh[t - off] : 0;
        __syncthreads();
        sh[t] += tv;
        __syncthreads();
    }
    if (t < nb) bofs[t] = sh[t] - v;
}

__global__ void k_scan3(int* __restrict__ arr, const int* __restrict__ bofs, int L) {
    int i = blockIdx.x * blockDim.x + threadIdx.x;
    if (i < L) arr[i] += bofs[i >> 10];
}

// ------------------------------------------------------- graph build, pass B
#define PBT 4096
__global__ __launch_bounds__(256) void k_part(const int* __restrict__ src,
                                              const int* __restrict__ dst,
                                              const int* __restrict__ T2,
                                              unsigned* __restrict__ eb,
                                              int E, int NB, int chunk) {
    __shared__ int hist[512], lexc[512], pos[512], wpos[512];
    __shared__ unsigned sorted[PBT];
    const int t = threadIdx.x;
    const int blk = blockIdx.x;
    const int lo = blk * chunk, hi = min(E, lo + chunk);
    for (int i = t; i < NB; i += 256) wpos[i] = T2[i * 256 + blk];
    __syncthreads();
    for (int tlo = lo; tlo < hi; tlo += PBT) {
        const int thi = min(hi, tlo + PBT);
        const int sz = thi - tlo;
        for (int i = t; i < 512; i += 256) hist[i] = 0;
        __syncthreads();
        for (int e = tlo + t; e < thi; e += 256)
            atomicAdd(&hist[dst[e] >> 7], 1);
        __syncthreads();
        const int i0 = t, i1 = t + 256;
        const int o0 = hist[i0], o1 = hist[i1];
        for (int off = 1; off < 512; off <<= 1) {
            int v0 = (i0 >= off) ? hist[i0 - off] : 0;
            int v1 = (i1 >= off) ? hist[i1 - off] : 0;
            __syncthreads();
            hist[i0] += v0;
            hist[i1] += v1;
            __syncthreads();
        }
        lexc[i0] = hist[i0] - o0; pos[i0] = hist[i0] - o0;
        lexc[i1] = hist[i1] - o1; pos[i1] = hist[i1] - o1;
        __syncthreads();
        for (int e = tlo + t; e < thi; e += 256) {
            int d = dst[e];
            int p = atomicAdd(&pos[d >> 7], 1);
            sorted[p] = ((unsigned)d << 16) | (unsigned)src[e];
        }
        __syncthreads();
        for (int i = t; i < sz; i += 256) {
            unsigned x = sorted[i];
            int b = (int)(x >> 23);
            eb[wpos[b] + (i - lexc[b])] = x;
        }
        __syncthreads();
        wpos[i0] += o0;
        wpos[i1] += o1;
        __syncthreads();
    }
}

// ------------------------------------------------------- graph build, pass C
#define PCT 6144
__global__ __launch_bounds__(256) void k_build(const unsigned* __restrict__ eb,
                                               const int* __restrict__ T2,
                                               unsigned short* __restrict__ csr,
                                               int* __restrict__ rofs,
                                               float* __restrict__ dinv,
                                               int N, int E, int NB) {
    __shared__ int hist[128], lofs[128], pos[128];
    __shared__ unsigned short ssrc[PCT];
    const int t = threadIdx.x;
    const int b = blockIdx.x;
    const int glo = T2[b * 256];
    const int ghi = (b + 1 < NB) ? T2[(b + 1) * 256] : E;
    const int sz = ghi - glo;
    if (t < 128) hist[t] = 0;
    __syncthreads();
    for (int i = t; i < sz; i += 256)
        atomicAdd(&hist[(eb[glo + i] >> 16) & 127], 1);
    __syncthreads();
    const int o = (t < 128) ? hist[t] : 0;
    for (int off = 1; off < 128; off <<= 1) {
        int v = (t < 128 && t >= off) ? hist[t - off] : 0;
        __syncthreads();
        if (t < 128) hist[t] += v;
        __syncthreads();
    }
    if (t < 128) {
        int ex = hist[t] - o;
        lofs[t] = ex;
        pos[t] = ex;
        int d = b * 128 + t;
        if (d < N) {
            rofs[d] = glo + ex;
            dinv[d] = rsqrtf((float)(o + 1));
        }
    }
    __syncthreads();
    if (sz <= PCT) {
        for (int i = t; i < sz; i += 256) {
            unsigned x = eb[glo + i];
            int p = atomicAdd(&pos[(x >> 16) & 127], 1);
            ssrc[p] = (unsigned short)(x & 0xFFFFu);
        }
        __syncthreads();
        for (int i = t; i < sz; i += 256) csr[glo + i] = ssrc[i];
    } else {
        for (int i = t; i < sz; i += 256) {
            unsigned x = eb[glo + i];
            int p = atomicAdd(&pos[(x >> 16) & 127], 1);
            csr[glo + p] = (unsigned short)(x & 0xFFFFu);
        }
    }
    if (b == 0 && t == 0) rofs[N] = E;
}

// --------------------------------------------- fused weight packing + init
// W[K][M] fp32 -> fp16 in MFMA B-frag order (layout identical to R7).
__device__ __forceinline__ void packw_tile(const float* W, _Float16* Wp,
                                           int K, int M, int c, int q, int l) {
    int n = c * 16 + (l & 15);
    int k0 = q * 32 + (l >> 4) * 8;
    size_t base = ((size_t)(c * (K / 32) + q) * 64 + l) * 8;
#pragma unroll
    for (int j = 0; j < 8; ++j)
        Wp[base + j] = (_Float16)W[(size_t)(k0 + j) * M + n];
}

__global__ __launch_bounds__(64) void k_pack_all(const float* __restrict__ W0,
                                                 const float* __restrict__ W1,
                                                 const float* __restrict__ W2,
                                                 const float* __restrict__ Wl,
                                                 _Float16* __restrict__ w0p,
                                                 _Float16* __restrict__ w1p,
                                                 _Float16* __restrict__ w2p,
                                                 _Float16* __restrict__ wlp,
                                                 unsigned* __restrict__ gmax) {
    int b = blockIdx.x, l = threadIdx.x;
    if (b < 64) {                       // W0: 256x128, 8 ctiles x 8 qtiles
        packw_tile(W0, w0p, 256, 128, b & 7, b >> 3, l);
    } else if (b < 96) {                // W1: 128x128
        int bb = b - 64;
        packw_tile(W1, w1p, 128, 128, bb & 7, bb >> 3, l);
    } else if (b < 128) {               // W2: 128x128
        int bb = b - 96;
        packw_tile(W2, w2p, 128, 128, bb & 7, bb >> 3, l);
    } else if (b < 144) {               // Wlin: 128x64, 4 ctiles x 4 qtiles
        int bb = b - 128;
        packw_tile(Wl, wlp, 128, 64, bb & 3, bb >> 2, l);
    } else {                            // gmax init
        gmax[l] = ENC_NEG_INF;
    }
}

// -------------------------------------------------------------------- GEMM
// 96-row block tile, 4 waves in 2x2 (wave: 48 rows x M/2 cols).
// KB = min(K,128) per stage; LDS: As[96*KB] (frag order, XOR-swizzled),
// Bs[M*KB] (pre-packed frag order). One barrier per stage.
// ADT=0: A fp32 [N][K].  ADT=1: A fp16 [N][K].
// EPI=0: out fp16[N][M] = (half)(sc[r] * A W).  EPI=1: global max pool.
template <int K, int M, int EPI, int ADT>
__global__ __launch_bounds__(256, 2) void k_gemm(const void* __restrict__ Av,
                                                 const _Float16* __restrict__ Wp,
                                                 const float* __restrict__ sc,
                                                 _Float16* __restrict__ out,
                                                 unsigned* __restrict__ gmax,
                                                 int N) {
    constexpr int KB = (K > 128) ? 128 : K;   // k per stage
    constexpr int NQ = K / KB;                // stages
    constexpr int NK = KB / 32;               // mfma k-steps per stage
    constexpr int KG = KB / 8;                // 8-half k-groups per stage
    constexpr int CT = M / 32;                // col tiles per wave
    constexpr int RT = 3;                     // row tiles per wave (48 rows)
    __shared__ _Float16 As[96 * KB];
    __shared__ _Float16 Bs[M * KB];
    __shared__ unsigned smax[64];
    const int tid = threadIdx.x;
    const int lane = tid & 63;
    const int wave = tid >> 6;
    const int wrow = wave >> 1;
    const int wcol = wave & 1;
    const int R0 = blockIdx.x * 96;

    f32x4 acc[RT][CT];
#pragma unroll
    for (int rt = 0; rt < RT; ++rt)
#pragma unroll
        for (int ct = 0; ct < CT; ++ct) acc[rt][ct] = (f32x4){0.f, 0.f, 0.f, 0.f};

    for (int q = 0; q < NQ; ++q) {
        if (q) __syncthreads();
        // ---- stage A ----
        if (ADT == 0) {
            const float* A = (const float*)Av;
#pragma unroll
            for (int it = 0; it < (96 * KB) / (4 * 256); ++it) {
                int idx = tid + it * 256;
                int r = idx >> 5;          // KB/4 = 32 float4 per row
                int f4 = idx & 31;
                float4 g = {0.f, 0.f, 0.f, 0.f};
                if (R0 + r < N) g = *(const float4*)&A[(size_t)(R0 + r) * K + q * KB + f4 * 4];
                int kg = f4 >> 1, sub = f4 & 1;
                f16x4 h;
                h[0] = (_Float16)g.x; h[1] = (_Float16)g.y;
                h[2] = (_Float16)g.z; h[3] = (_Float16)g.w;
                *(f16x4*)&As[(r >> 4) * (KG * 128) + kg * 128 + (((r & 15) ^ kg) * 8) + sub * 4] = h;
            }
        } else {
            const _Float16* A = (const _Float16*)Av;
#pragma unroll
            for (int it = 0; it < (96 * KB) / (8 * 256); ++it) {
                int idx = tid + it * 256;
                int r = idx / KG;
                int kg = idx % KG;
                uint4 g = {0u, 0u, 0u, 0u};
                if (R0 + r < N) g = *(const uint4*)&A[(size_t)(R0 + r) * K + q * KB + kg * 8];
                *(uint4*)&As[(r >> 4) * (KG * 128) + kg * 128 + (((r & 15) ^ kg) * 8)] = g;
            }
        }
        // ---- stage B: contiguous copy of pre-packed region ----
#pragma unroll
        for (int it = 0; it < (M * KB) / (8 * 256); ++it) {
            int u = tid + it * 256;
            int c = u / (NK * 64);
            int rem = u % (NK * 64);
            *(uint4*)&Bs[u * 8] =
                *(const uint4*)&Wp[((size_t)(c * (K / 32) + q * NK) * 64) * 8 + (size_t)rem * 8];
        }
        __syncthreads();
        // ---- compute: NK k-steps, straight-line MFMAs ----
#pragma unroll
        for (int qq = 0; qq < NK; ++qq) {
            const int kgq = qq * 4 + (lane >> 4);
            f16x8 af[RT], bf[CT];
#pragma unroll
            for (int rt = 0; rt < RT; ++rt) {
                int tr = wrow * RT + rt;
                af[rt] = *(const f16x8*)&As[tr * (KG * 128) + kgq * 128 + (((lane & 15) ^ kgq) * 8)];
            }
#pragma unroll
            for (int ct = 0; ct < CT; ++ct)
                bf[ct] = *(const f16x8*)&Bs[(wcol * CT + ct) * (NK * 512) + qq * 512 + lane * 8];
#pragma unroll
            for (int rt = 0; rt < RT; ++rt)
#pragma unroll
                for (int ct = 0; ct < CT; ++ct)
                    acc[rt][ct] = __builtin_amdgcn_mfma_f32_16x16x32_f16(af[rt], bf[ct], acc[rt][ct], 0, 0, 0);
        }
    }

    const int quad = lane >> 4;
    if (EPI == 0) {
#pragma unroll
        for (int rt = 0; rt < RT; ++rt)
#pragma unroll
            for (int reg = 0; reg < 4; ++reg) {
                int r = R0 + wrow * 48 + rt * 16 + quad * 4 + reg;
                if (r < N) {
                    float s = sc[r];
#pragma unroll
                    for (int ct = 0; ct < CT; ++ct) {
                        int c = wcol * (CT * 16) + ct * 16 + (lane & 15);
                        out[(size_t)r * M + c] = (_Float16)(acc[rt][ct][reg] * s);
                    }
                }
            }
    } else {
        if (tid < 64) smax[tid] = ENC_NEG_INF;
        __syncthreads();
        float cm[CT];
#pragma unroll
        for (int ct = 0; ct < CT; ++ct) cm[ct] = -INFINITY;
#pragma unroll
        for (int rt = 0; rt < RT; ++rt)
#pragma unroll
            for (int reg = 0; reg < 4; ++reg) {
                int r = R0 + wrow * 48 + rt * 16 + quad * 4 + reg;
                if (r < N) {
#pragma unroll
                    for (int ct = 0; ct < CT; ++ct) cm[ct] = fmaxf(cm[ct], acc[rt][ct][reg]);
                }
            }
#pragma unroll
        for (int ct = 0; ct < CT; ++ct) {
            float v = cm[ct];
            v = fmaxf(v, __shfl_xor(v, 16, 64));
            v = fmaxf(v, __shfl_xor(v, 32, 64));
            if (lane < 16) {
                int c = wcol * (CT * 16) + ct * 16 + lane;
                atomicMax(&smax[c], enc_f32(v + sc[c]));
            }
        }
        __syncthreads();
        if (tid < 64) atomicMax(&gmax[tid], smax[tid]);
    }
}

__global__ void k_decode(const unsigned* __restrict__ g, float* __restrict__ out) {
    out[threadIdx.x] = dec_f32(g[threadIdx.x]);
}

// ------------------------------------------------------------- aggregation
__global__ __launch_bounds__(256) void k_agg(const _Float16* __restrict__ tmp,
                                             const float* __restrict__ dinv,
                                             const int* __restrict__ rofs,
                                             const unsigned short* __restrict__ csr,
                                             const float* __restrict__ bias,
                                             _Float16* __restrict__ out, int N) {
    const int lane = threadIdx.x & 63;
    const int d = blockIdx.x * 4 + (threadIdx.x >> 6);
    if (d >= N) return;
    const int eh = lane >> 4;
    const int fl = lane & 15;
    const int beg = rofs[d], end = rofs[d + 1];
    float a[8];
#pragma unroll
    for (int j = 0; j < 8; ++j) a[j] = 0.f;

    int e = beg;
    for (; e + 16 <= end; e += 16) {
        int s0 = csr[e + eh];
        int s1 = csr[e + 4 + eh];
        int s2 = csr[e + 8 + eh];
        int s3 = csr[e + 12 + eh];
        f16x8 v0 = *(const f16x8*)&tmp[(size_t)s0 * 128 + fl * 8];
        f16x8 v1 = *(const f16x8*)&tmp[(size_t)s1 * 128 + fl * 8];
        f16x8 v2 = *(const f16x8*)&tmp[(size_t)s2 * 128 + fl * 8];
        f16x8 v3 = *(const f16x8*)&tmp[(size_t)s3 * 128 + fl * 8];
#pragma unroll
        for (int j = 0; j < 8; ++j) a[j] += (float)v0[j];
#pragma unroll
        for (int j = 0; j < 8; ++j) a[j] += (float)v1[j];
#pragma unroll
        for (int j = 0; j < 8; ++j) a[j] += (float)v2[j];
#pragma unroll
        for (int j = 0; j < 8; ++j) a[j] += (float)v3[j];
    }
    for (; e + 4 <= end; e += 4) {
        int s = csr[e + eh];
        f16x8 v = *(const f16x8*)&tmp[(size_t)s * 128 + fl * 8];
#pragma unroll
        for (int j = 0; j < 8; ++j) a[j] += (float)v[j];
    }
    if (eh < end - e) {
        int s = csr[e + eh];
        f16x8 v = *(const f16x8*)&tmp[(size_t)s * 128 + fl * 8];
#pragma unroll
        for (int j = 0; j < 8; ++j) a[j] += (float)v[j];
    }
    if (eh == 3) {  // self-loop
        f16x8 v = *(const f16x8*)&tmp[(size_t)d * 128 + fl * 8];
#pragma unroll
        for (int j = 0; j < 8; ++j) a[j] += (float)v[j];
    }
#pragma unroll
    for (int j = 0; j < 8; ++j) {
        a[j] += __shfl_xor(a[j], 16, 64);
        a[j] += __shfl_xor(a[j], 32, 64);
    }
    if (eh == 0) {
        float di = dinv[d];
        float4 b0 = *(const float4*)&bias[fl * 8];
        float4 b1 = *(const float4*)&bias[fl * 8 + 4];
        f16x8 o;
        o[0] = (_Float16)fmaf(di, a[0], b0.x);
        o[1] = (_Float16)fmaf(di, a[1], b0.y);
        o[2] = (_Float16)fmaf(di, a[2], b0.z);
        o[3] = (_Float16)fmaf(di, a[3], b0.w);
        o[4] = (_Float16)fmaf(di, a[4], b1.x);
        o[5] = (_Float16)fmaf(di, a[5], b1.y);
        o[6] = (_Float16)fmaf(di, a[6], b1.z);
        o[7] = (_Float16)fmaf(di, a[7], b1.w);
        *(f16x8*)&out[(size_t)d * 128 + fl * 8] = o;
    }
}

// ---------------------------------------------------------------------------
extern "C" void kernel_launch(void* const* d_in, const int* in_sizes, int n_in,
                              void* d_out, int out_size, void* d_ws, size_t ws_size,
                              hipStream_t stream) {
    const float* x    = (const float*)d_in[0];
    const int*   ei   = (const int*)d_in[1];  // [2,E]: row0=src, row1=dst
    const float* W0   = (const float*)d_in[3];
    const float* b0   = (const float*)d_in[4];
    const float* W1   = (const float*)d_in[5];
    const float* b1   = (const float*)d_in[6];
    const float* W2   = (const float*)d_in[7];
    const float* b2   = (const float*)d_in[8];
    const float* Wlin = (const float*)d_in[9];
    const float* blin = (const float*)d_in[10];
    float* out = (float*)d_out;

    const int N = in_sizes[2];
    const int E = in_sizes[1] / 2;
    const int* src = ei;
    const int* dst = ei + E;

    size_t off = 0;
    auto carve = [&](size_t bytes) {
        void* p = (char*)d_ws + off;
        off += (bytes + 255) & ~(size_t)255;
        return p;
    };
    const int NB    = (N + 127) / 128;
    const int L     = NB * 256;
    const int chunk = (E + 255) / 256;

    float*          dinv = (float*)carve((size_t)N * 4);
    int*            rofs = (int*)carve((size_t)(N + 1) * 4);
    int*            T    = (int*)carve((size_t)L * 4);
    int*            T2   = (int*)carve((size_t)L * 4);
    int*            bsums = (int*)carve(1024 * 4);
    int*            bofs  = (int*)carve(1024 * 4);
    unsigned*       eb   = (unsigned*)carve((size_t)E * 4);
    unsigned short* csr  = (unsigned short*)carve((size_t)E * 2);
    _Float16*       tmpA = (_Float16*)carve((size_t)N * 128 * 2);
    _Float16*       tmpB = (_Float16*)carve((size_t)N * 128 * 2);
    unsigned*       gmax = (unsigned*)carve(64 * 4);
    _Float16*       w0p  = (_Float16*)carve(256 * 128 * 2);
    _Float16*       w1p  = (_Float16*)carve(128 * 128 * 2);
    _Float16*       w2p  = (_Float16*)carve(128 * 128 * 2);
    _Float16*       wlp  = (_Float16*)carve(128 * 64 * 2);
    (void)ws_size; (void)n_in; (void)out_size;

    const int nbG  = (N + 95) / 96;   // 96-row gemm tiles
    const int nbAg = (N + 3) / 4;
    const int nbS  = (L + 1023) / 1024;

    // fused weight packing + gmax init (145 tiny blocks)
    k_pack_all<<<145, 64, 0, stream>>>(W0, W1, W2, Wlin, w0p, w1p, w2p, wlp, gmax);

    // graph build: hist -> scan(T) -> partition -> per-bucket counting sort
    k_hist<<<256, 256, 0, stream>>>(dst, T, E, NB, chunk);
    k_scan1<<<nbS, 1024, 0, stream>>>(T, T2, bsums, L);
    k_scan2<<<1, 1024, 0, stream>>>(bsums, bofs, nbS);
    k_scan3<<<(L + 255) / 256, 256, 0, stream>>>(T2, bofs, L);
    k_part<<<256, 256, 0, stream>>>(src, dst, T2, eb, E, NB, chunk);
    k_build<<<NB, 256, 0, stream>>>(eb, T2, csr, rofs, dinv, N, E, NB);

    // layer 1 (A = fp32 x)
    k_gemm<256, 128, 0, 0><<<nbG, 256, 0, stream>>>(x, w0p, dinv, tmpA, nullptr, N);
    k_agg<<<nbAg, 256, 0, stream>>>(tmpA, dinv, rofs, csr, b0, tmpB, N);
    // layer 2
    k_gemm<128, 128, 0, 1><<<nbG, 256, 0, stream>>>(tmpB, w1p, dinv, tmpA, nullptr, N);
    k_agg<<<nbAg, 256, 0, stream>>>(tmpA, dinv, rofs, csr, b1, tmpB, N);
    // layer 3
    k_gemm<128, 128, 0, 1><<<nbG, 256, 0, stream>>>(tmpB, w2p, dinv, tmpA, nullptr, N);
    k_agg<<<nbAg, 256, 0, stream>>>(tmpA, dinv, rofs, csr, b2, tmpB, N);
    // linear + global max pool
    k_gemm<128, 64, 1, 1><<<nbG, 256, 0, stream>>>(tmpB, wlp, blin, nullptr, gmax, N);
    k_decode<<<1, 64, 0, stream>>>(gmax, out);
}

// Round 9
// 301.641 us; speedup vs baseline: 2.0109x; 1.0053x over previous
//
#include <hip/hip_runtime.h>
#include <math.h>

// ---------------------------------------------------------------------------
// GCN forward: 3x GCNConv (sym-norm, self-loops) + linear + global max pool.
// N=50000, E=800000, F=256, H=128, O=64. fp32 in/out, fp16 intermediates.
//
// R9: GEMM B-tile no longer staged in LDS — B frags load straight from the
// pre-packed global buffer (L2-resident, coalesced 16B/lane). LDS = A only
// (24 KB) -> launch_bounds(256,4) = 4 blocks/CU = 16 waves/CU for latency
// hiding (R8 was 2 blocks/CU, Occupancy 11%, MfmaUtil 2.6% = latency-bound).
// 96-row tiles (521 blocks = 2 full rounds + spares at 4/CU).
// ---------------------------------------------------------------------------

typedef __attribute__((ext_vector_type(8))) _Float16 f16x8;
typedef __attribute__((ext_vector_type(4))) _Float16 f16x4;
typedef __attribute__((ext_vector_type(4))) float f32x4;

__device__ __forceinline__ unsigned enc_f32(float f) {
    unsigned u = __float_as_uint(f);
    return (u & 0x80000000u) ? ~u : (u | 0x80000000u);
}
__device__ __forceinline__ float dec_f32(unsigned e) {
    return (e & 0x80000000u) ? __uint_as_float(e & 0x7fffffffu)
                             : __uint_as_float(~e);
}
#define ENC_NEG_INF 0x007FFFFFu  // enc(-inf)

// ------------------------------------------------------- graph build, pass A
__global__ __launch_bounds__(256) void k_hist(const int* __restrict__ dst,
                                              int* __restrict__ T,
                                              int E, int NB, int chunk) {
    __shared__ int hist[512];
    for (int i = threadIdx.x; i < 512; i += 256) hist[i] = 0;
    __syncthreads();
    const int lo = blockIdx.x * chunk, hi = min(E, lo + chunk);
    for (int e = lo + threadIdx.x; e < hi; e += 256)
        atomicAdd(&hist[dst[e] >> 7], 1);
    __syncthreads();
    for (int b = threadIdx.x; b < NB; b += 256)
        T[b * 256 + blockIdx.x] = hist[b];
}

// ------------------------------------------------------------- 3-pass scan
__global__ __launch_bounds__(1024) void k_scan1(const int* __restrict__ in,
                                                int* __restrict__ excl,
                                                int* __restrict__ bsums, int L) {
    __shared__ int sh[1024];
    int t = threadIdx.x;
    int i = blockIdx.x * 1024 + t;
    int v = (i < L) ? in[i] : 0;
    sh[t] = v;
    __syncthreads();
    for (int off = 1; off < 1024; off <<= 1) {
        int tv = (t >= off) ? sh[t - off] : 0;
        __syncthreads();
        sh[t] += tv;
        __syncthreads();
    }
    if (i < L) excl[i] = sh[t] - v;
    if (t == 1023) bsums[blockIdx.x] = sh[1023];
}

__global__ __launch_bounds__(1024) void k_scan2(const int* __restrict__ bsums,
                                                int* __restrict__ bofs, int nb) {
    __shared__ int sh[1024];
    int t = threadIdx.x;
    int v = (t < nb) ? bsums[t] : 0;
    sh[t] = v;
    __syncthreads();
    for (int off = 1; off < 1024; off <<= 1) {
        int tv = (t >= off) ? sh[t - off] : 0;
        __syncthreads();
        sh[t] += tv;
        __syncthreads();
    }
    if (t < nb) bofs[t] = sh[t] - v;
}

__global__ void k_scan3(int* __restrict__ arr, const int* __restrict__ bofs, int L) {
    int i = blockIdx.x * blockDim.x + threadIdx.x;
    if (i < L) arr[i] += bofs[i >> 10];
}

// ------------------------------------------------------- graph build, pass B
#define PBT 4096
__global__ __launch_bounds__(256) void k_part(const int* __restrict__ src,
                                              const int* __restrict__ dst,
                                              const int* __restrict__ T2,
                                              unsigned* __restrict__ eb,
                                              int E, int NB, int chunk) {
    __shared__ int hist[512], lexc[512], pos[512], wpos[512];
    __shared__ unsigned sorted[PBT];
    const int t = threadIdx.x;
    const int blk = blockIdx.x;
    const int lo = blk * chunk, hi = min(E, lo + chunk);
    for (int i = t; i < NB; i += 256) wpos[i] = T2[i * 256 + blk];
    __syncthreads();
    for (int tlo = lo; tlo < hi; tlo += PBT) {
        const int thi = min(hi, tlo + PBT);
        const int sz = thi - tlo;
        for (int i = t; i < 512; i += 256) hist[i] = 0;
        __syncthreads();
        for (int e = tlo + t; e < thi; e += 256)
            atomicAdd(&hist[dst[e] >> 7], 1);
        __syncthreads();
        const int i0 = t, i1 = t + 256;
        const int o0 = hist[i0], o1 = hist[i1];
        for (int off = 1; off < 512; off <<= 1) {
            int v0 = (i0 >= off) ? hist[i0 - off] : 0;
            int v1 = (i1 >= off) ? hist[i1 - off] : 0;
            __syncthreads();
            hist[i0] += v0;
            hist[i1] += v1;
            __syncthreads();
        }
        lexc[i0] = hist[i0] - o0; pos[i0] = hist[i0] - o0;
        lexc[i1] = hist[i1] - o1; pos[i1] = hist[i1] - o1;
        __syncthreads();
        for (int e = tlo + t; e < thi; e += 256) {
            int d = dst[e];
            int p = atomicAdd(&pos[d >> 7], 1);
            sorted[p] = ((unsigned)d << 16) | (unsigned)src[e];
        }
        __syncthreads();
        for (int i = t; i < sz; i += 256) {
            unsigned x = sorted[i];
            int b = (int)(x >> 23);
            eb[wpos[b] + (i - lexc[b])] = x;
        }
        __syncthreads();
        wpos[i0] += o0;
        wpos[i1] += o1;
        __syncthreads();
    }
}

// ------------------------------------------------------- graph build, pass C
#define PCT 6144
__global__ __launch_bounds__(256) void k_build(const unsigned* __restrict__ eb,
                                               const int* __restrict__ T2,
                                               unsigned short* __restrict__ csr,
                                               int* __restrict__ rofs,
                                               float* __restrict__ dinv,
                                               int N, int E, int NB) {
    __shared__ int hist[128], lofs[128], pos[128];
    __shared__ unsigned short ssrc[PCT];
    const int t = threadIdx.x;
    const int b = blockIdx.x;
    const int glo = T2[b * 256];
    const int ghi = (b + 1 < NB) ? T2[(b + 1) * 256] : E;
    const int sz = ghi - glo;
    if (t < 128) hist[t] = 0;
    __syncthreads();
    for (int i = t; i < sz; i += 256)
        atomicAdd(&hist[(eb[glo + i] >> 16) & 127], 1);
    __syncthreads();
    const int o = (t < 128) ? hist[t] : 0;
    for (int off = 1; off < 128; off <<= 1) {
        int v = (t < 128 && t >= off) ? hist[t - off] : 0;
        __syncthreads();
        if (t < 128) hist[t] += v;
        __syncthreads();
    }
    if (t < 128) {
        int ex = hist[t] - o;
        lofs[t] = ex;
        pos[t] = ex;
        int d = b * 128 + t;
        if (d < N) {
            rofs[d] = glo + ex;
            dinv[d] = rsqrtf((float)(o + 1));
        }
    }
    __syncthreads();
    if (sz <= PCT) {
        for (int i = t; i < sz; i += 256) {
            unsigned x = eb[glo + i];
            int p = atomicAdd(&pos[(x >> 16) & 127], 1);
            ssrc[p] = (unsigned short)(x & 0xFFFFu);
        }
        __syncthreads();
        for (int i = t; i < sz; i += 256) csr[glo + i] = ssrc[i];
    } else {
        for (int i = t; i < sz; i += 256) {
            unsigned x = eb[glo + i];
            int p = atomicAdd(&pos[(x >> 16) & 127], 1);
            csr[glo + p] = (unsigned short)(x & 0xFFFFu);
        }
    }
    if (b == 0 && t == 0) rofs[N] = E;
}

// --------------------------------------------- fused weight packing + init
__device__ __forceinline__ void packw_tile(const float* W, _Float16* Wp,
                                           int K, int M, int c, int q, int l) {
    int n = c * 16 + (l & 15);
    int k0 = q * 32 + (l >> 4) * 8;
    size_t base = ((size_t)(c * (K / 32) + q) * 64 + l) * 8;
#pragma unroll
    for (int j = 0; j < 8; ++j)
        Wp[base + j] = (_Float16)W[(size_t)(k0 + j) * M + n];
}

__global__ __launch_bounds__(64) void k_pack_all(const float* __restrict__ W0,
                                                 const float* __restrict__ W1,
                                                 const float* __restrict__ W2,
                                                 const float* __restrict__ Wl,
                                                 _Float16* __restrict__ w0p,
                                                 _Float16* __restrict__ w1p,
                                                 _Float16* __restrict__ w2p,
                                                 _Float16* __restrict__ wlp,
                                                 unsigned* __restrict__ gmax) {
    int b = blockIdx.x, l = threadIdx.x;
    if (b < 64) {
        packw_tile(W0, w0p, 256, 128, b & 7, b >> 3, l);
    } else if (b < 96) {
        int bb = b - 64;
        packw_tile(W1, w1p, 128, 128, bb & 7, bb >> 3, l);
    } else if (b < 128) {
        int bb = b - 96;
        packw_tile(W2, w2p, 128, 128, bb & 7, bb >> 3, l);
    } else if (b < 144) {
        int bb = b - 128;
        packw_tile(Wl, wlp, 128, 64, bb & 3, bb >> 2, l);
    } else {
        gmax[l] = ENC_NEG_INF;
    }
}

// -------------------------------------------------------------------- GEMM
// 96-row block tile, 4 waves in 2x2 (wave: 48 rows x M/2 cols).
// A staged in LDS (XOR-swizzled frag order), KB=128 per stage.
// B frags read DIRECTLY from pre-packed global Wp (L2-resident, coalesced).
// ADT=0: A fp32 [N][K].  ADT=1: A fp16 [N][K].
// EPI=0: out fp16[N][M] = (half)(sc[r] * A W).  EPI=1: global max pool.
template <int K, int M, int EPI, int ADT>
__global__ __launch_bounds__(256, 4) void k_gemm(const void* __restrict__ Av,
                                                 const _Float16* __restrict__ Wp,
                                                 const float* __restrict__ sc,
                                                 _Float16* __restrict__ out,
                                                 unsigned* __restrict__ gmax,
                                                 int N) {
    constexpr int KB = (K > 128) ? 128 : K;   // k per stage
    constexpr int NQ = K / KB;                // stages
    constexpr int NK = KB / 32;               // mfma k-steps per stage
    constexpr int KG = KB / 8;                // 8-half k-groups per stage
    constexpr int CT = M / 32;                // col tiles per wave
    constexpr int RT = 3;                     // row tiles per wave (48 rows)
    __shared__ _Float16 As[96 * KB];          // 24 KB
    __shared__ unsigned smax[64];
    const int tid = threadIdx.x;
    const int lane = tid & 63;
    const int wave = tid >> 6;
    const int wrow = wave >> 1;
    const int wcol = wave & 1;
    const int R0 = blockIdx.x * 96;

    f32x4 acc[RT][CT];
#pragma unroll
    for (int rt = 0; rt < RT; ++rt)
#pragma unroll
        for (int ct = 0; ct < CT; ++ct) acc[rt][ct] = (f32x4){0.f, 0.f, 0.f, 0.f};

    for (int q = 0; q < NQ; ++q) {
        if (q) __syncthreads();
        // ---- stage A into LDS ----
        if (ADT == 0) {
            const float* A = (const float*)Av;
#pragma unroll
            for (int it = 0; it < (96 * KB) / (4 * 256); ++it) {
                int idx = tid + it * 256;
                int r = idx >> 5;
                int f4 = idx & 31;
                float4 g = {0.f, 0.f, 0.f, 0.f};
                if (R0 + r < N) g = *(const float4*)&A[(size_t)(R0 + r) * K + q * KB + f4 * 4];
                int kg = f4 >> 1, sub = f4 & 1;
                f16x4 h;
                h[0] = (_Float16)g.x; h[1] = (_Float16)g.y;
                h[2] = (_Float16)g.z; h[3] = (_Float16)g.w;
                *(f16x4*)&As[(r >> 4) * (KG * 128) + kg * 128 + (((r & 15) ^ kg) * 8) + sub * 4] = h;
            }
        } else {
            const _Float16* A = (const _Float16*)Av;
#pragma unroll
            for (int it = 0; it < (96 * KB) / (8 * 256); ++it) {
                int idx = tid + it * 256;
                int r = idx / KG;
                int kg = idx % KG;
                uint4 g = {0u, 0u, 0u, 0u};
                if (R0 + r < N) g = *(const uint4*)&A[(size_t)(R0 + r) * K + q * KB + kg * 8];
                *(uint4*)&As[(r >> 4) * (KG * 128) + kg * 128 + (((r & 15) ^ kg) * 8)] = g;
            }
        }
        __syncthreads();
        // ---- compute: NK k-steps; B frags straight from global (L2) ----
#pragma unroll
        for (int qq = 0; qq < NK; ++qq) {
            const int kk = q * NK + qq;           // global 32-k chunk index
            const int kgq = qq * 4 + (lane >> 4);
            f16x8 af[RT], bf[CT];
#pragma unroll
            for (int ct = 0; ct < CT; ++ct) {
                int t = wcol * CT + ct;
                bf[ct] = *(const f16x8*)&Wp[((size_t)(t * (K / 32) + kk) * 64 + lane) * 8];
            }
#pragma unroll
            for (int rt = 0; rt < RT; ++rt) {
                int tr = wrow * RT + rt;
                af[rt] = *(const f16x8*)&As[tr * (KG * 128) + kgq * 128 + (((lane & 15) ^ kgq) * 8)];
            }
#pragma unroll
            for (int rt = 0; rt < RT; ++rt)
#pragma unroll
                for (int ct = 0; ct < CT; ++ct)
                    acc[rt][ct] = __builtin_amdgcn_mfma_f32_16x16x32_f16(af[rt], bf[ct], acc[rt][ct], 0, 0, 0);
        }
    }

    const int quad = lane >> 4;
    if (EPI == 0) {
#pragma unroll
        for (int rt = 0; rt < RT; ++rt)
#pragma unroll
            for (int reg = 0; reg < 4; ++reg) {
                int r = R0 + wrow * 48 + rt * 16 + quad * 4 + reg;
                if (r < N) {
                    float s = sc[r];
#pragma unroll
                    for (int ct = 0; ct < CT; ++ct) {
                        int c = wcol * (CT * 16) + ct * 16 + (lane & 15);
                        out[(size_t)r * M + c] = (_Float16)(acc[rt][ct][reg] * s);
                    }
                }
            }
    } else {
        if (tid < 64) smax[tid] = ENC_NEG_INF;
        __syncthreads();
        float cm[CT];
#pragma unroll
        for (int ct = 0; ct < CT; ++ct) cm[ct] = -INFINITY;
#pragma unroll
        for (int rt = 0; rt < RT; ++rt)
#pragma unroll
            for (int reg = 0; reg < 4; ++reg) {
                int r = R0 + wrow * 48 + rt * 16 + quad * 4 + reg;
                if (r < N) {
#pragma unroll
                    for (int ct = 0; ct < CT; ++ct) cm[ct] = fmaxf(cm[ct], acc[rt][ct][reg]);
                }
            }
#pragma unroll
        for (int ct = 0; ct < CT; ++ct) {
            float v = cm[ct];
            v = fmaxf(v, __shfl_xor(v, 16, 64));
            v = fmaxf(v, __shfl_xor(v, 32, 64));
            if (lane < 16) {
                int c = wcol * (CT * 16) + ct * 16 + lane;
                atomicMax(&smax[c], enc_f32(v + sc[c]));
            }
        }
        __syncthreads();
        if (tid < 64) atomicMax(&gmax[tid], smax[tid]);
    }
}

__global__ void k_decode(const unsigned* __restrict__ g, float* __restrict__ out) {
    out[threadIdx.x] = dec_f32(g[threadIdx.x]);
}

// ------------------------------------------------------------- aggregation
__global__ __launch_bounds__(256) void k_agg(const _Float16* __restrict__ tmp,
                                             const float* __restrict__ dinv,
                                             const int* __restrict__ rofs,
                                             const unsigned short* __restrict__ csr,
                                             const float* __restrict__ bias,
                                             _Float16* __restrict__ out, int N) {
    const int lane = threadIdx.x & 63;
    const int d = blockIdx.x * 4 + (threadIdx.x >> 6);
    if (d >= N) return;
    const int eh = lane >> 4;
    const int fl = lane & 15;
    const int beg = rofs[d], end = rofs[d + 1];
    float a[8];
#pragma unroll
    for (int j = 0; j < 8; ++j) a[j] = 0.f;

    int e = beg;
    for (; e + 16 <= end; e += 16) {
        int s0 = csr[e + eh];
        int s1 = csr[e + 4 + eh];
        int s2 = csr[e + 8 + eh];
        int s3 = csr[e + 12 + eh];
        f16x8 v0 = *(const f16x8*)&tmp[(size_t)s0 * 128 + fl * 8];
        f16x8 v1 = *(const f16x8*)&tmp[(size_t)s1 * 128 + fl * 8];
        f16x8 v2 = *(const f16x8*)&tmp[(size_t)s2 * 128 + fl * 8];
        f16x8 v3 = *(const f16x8*)&tmp[(size_t)s3 * 128 + fl * 8];
#pragma unroll
        for (int j = 0; j < 8; ++j) a[j] += (float)v0[j];
#pragma unroll
        for (int j = 0; j < 8; ++j) a[j] += (float)v1[j];
#pragma unroll
        for (int j = 0; j < 8; ++j) a[j] += (float)v2[j];
#pragma unroll
        for (int j = 0; j < 8; ++j) a[j] += (float)v3[j];
    }
    for (; e + 4 <= end; e += 4) {
        int s = csr[e + eh];
        f16x8 v = *(const f16x8*)&tmp[(size_t)s * 128 + fl * 8];
#pragma unroll
        for (int j = 0; j < 8; ++j) a[j] += (float)v[j];
    }
    if (eh < end - e) {
        int s = csr[e + eh];
        f16x8 v = *(const f16x8*)&tmp[(size_t)s * 128 + fl * 8];
#pragma unroll
        for (int j = 0; j < 8; ++j) a[j] += (float)v[j];
    }
    if (eh == 3) {  // self-loop
        f16x8 v = *(const f16x8*)&tmp[(size_t)d * 128 + fl * 8];
#pragma unroll
        for (int j = 0; j < 8; ++j) a[j] += (float)v[j];
    }
#pragma unroll
    for (int j = 0; j < 8; ++j) {
        a[j] += __shfl_xor(a[j], 16, 64);
        a[j] += __shfl_xor(a[j], 32, 64);
    }
    if (eh == 0) {
        float di = dinv[d];
        float4 b0 = *(const float4*)&bias[fl * 8];
        float4 b1 = *(const float4*)&bias[fl * 8 + 4];
        f16x8 o;
        o[0] = (_Float16)fmaf(di, a[0], b0.x);
        o[1] = (_Float16)fmaf(di, a[1], b0.y);
        o[2] = (_Float16)fmaf(di, a[2], b0.z);
        o[3] = (_Float16)fmaf(di, a[3], b0.w);
        o[4] = (_Float16)fmaf(di, a[4], b1.x);
        o[5] = (_Float16)fmaf(di, a[5], b1.y);
        o[6] = (_Float16)fmaf(di, a[6], b1.z);
        o[7] = (_Float16)fmaf(di, a[7], b1.w);
        *(f16x8*)&out[(size_t)d * 128 + fl * 8] = o;
    }
}

// ---------------------------------------------------------------------------
extern "C" void kernel_launch(void* const* d_in, const int* in_sizes, int n_in,
                              void* d_out, int out_size, void* d_ws, size_t ws_size,
                              hipStream_t stream) {
    const float* x    = (const float*)d_in[0];
    const int*   ei   = (const int*)d_in[1];  // [2,E]: row0=src, row1=dst
    const float* W0   = (const float*)d_in[3];
    const float* b0   = (const float*)d_in[4];
    const float* W1   = (const float*)d_in[5];
    const float* b1   = (const float*)d_in[6];
    const float* W2   = (const float*)d_in[7];
    const float* b2   = (const float*)d_in[8];
    const float* Wlin = (const float*)d_in[9];
    const float* blin = (const float*)d_in[10];
    float* out = (float*)d_out;

    const int N = in_sizes[2];
    const int E = in_sizes[1] / 2;
    const int* src = ei;
    const int* dst = ei + E;

    size_t off = 0;
    auto carve = [&](size_t bytes) {
        void* p = (char*)d_ws + off;
        off += (bytes + 255) & ~(size_t)255;
        return p;
    };
    const int NB    = (N + 127) / 128;
    const int L     = NB * 256;
    const int chunk = (E + 255) / 256;

    float*          dinv = (float*)carve((size_t)N * 4);
    int*            rofs = (int*)carve((size_t)(N + 1) * 4);
    int*            T    = (int*)carve((size_t)L * 4);
    int*            T2   = (int*)carve((size_t)L * 4);
    int*            bsums = (int*)carve(1024 * 4);
    int*            bofs  = (int*)carve(1024 * 4);
    unsigned*       eb   = (unsigned*)carve((size_t)E * 4);
    unsigned short* csr  = (unsigned short*)carve((size_t)E * 2);
    _Float16*       tmpA = (_Float16*)carve((size_t)N * 128 * 2);
    _Float16*       tmpB = (_Float16*)carve((size_t)N * 128 * 2);
    unsigned*       gmax = (unsigned*)carve(64 * 4);
    _Float16*       w0p  = (_Float16*)carve(256 * 128 * 2);
    _Float16*       w1p  = (_Float16*)carve(128 * 128 * 2);
    _Float16*       w2p  = (_Float16*)carve(128 * 128 * 2);
    _Float16*       wlp  = (_Float16*)carve(128 * 64 * 2);
    (void)ws_size; (void)n_in; (void)out_size;

    const int nbG  = (N + 95) / 96;
    const int nbAg = (N + 3) / 4;
    const int nbS  = (L + 1023) / 1024;

    k_pack_all<<<145, 64, 0, stream>>>(W0, W1, W2, Wlin, w0p, w1p, w2p, wlp, gmax);

    // graph build: hist -> scan(T) -> partition -> per-bucket counting sort
    k_hist<<<256, 256, 0, stream>>>(dst, T, E, NB, chunk);
    k_scan1<<<nbS, 1024, 0, stream>>>(T, T2, bsums, L);
    k_scan2<<<1, 1024, 0, stream>>>(bsums, bofs, nbS);
    k_scan3<<<(L + 255) / 256, 256, 0, stream>>>(T2, bofs, L);
    k_part<<<256, 256, 0, stream>>>(src, dst, T2, eb, E, NB, chunk);
    k_build<<<NB, 256, 0, stream>>>(eb, T2, csr, rofs, dinv, N, E, NB);

    // layer 1 (A = fp32 x)
    k_gemm<256, 128, 0, 0><<<nbG, 256, 0, stream>>>(x, w0p, dinv, tmpA, nullptr, N);
    k_agg<<<nbAg, 256, 0, stream>>>(tmpA, dinv, rofs, csr, b0, tmpB, N);
    // layer 2
    k_gemm<128, 128, 0, 1><<<nbG, 256, 0, stream>>>(tmpB, w1p, dinv, tmpA, nullptr, N);
    k_agg<<<nbAg, 256, 0, stream>>>(tmpA, dinv, rofs, csr, b1, tmpB, N);
    // layer 3
    k_gemm<128, 128, 0, 1><<<nbG, 256, 0, stream>>>(tmpB, w2p, dinv, tmpA, nullptr, N);
    k_agg<<<nbAg, 256, 0, stream>>>(tmpA, dinv, rofs, csr, b2, tmpB, N);
    // linear + global max pool
    k_gemm<128, 64, 1, 1><<<nbG, 256, 0, stream>>>(tmpB, wlp, blin, nullptr, gmax, N);
    k_decode<<<1, 64, 0, stream>>>(gmax, out);
}